// Round 1
// baseline (3894.536 us; speedup 1.0000x reference)
//
#include <hip/hip_runtime.h>
#include <math.h>

#define NN 100000
#define EE 640000
#define GG 128
#define BN_EPS 1e-5f

// ---------------- ws layout (float offsets) ----------------
// A   : [0,        12,800,000)   N x 128
// B   : [12.8M,    25,600,000)   N x 128
// Z   : [25.6M,    +100,000)     N x 1 (layer-2 pre-BN scalar)
// SM  : [25.7M,    +770)         stats0(256) stats1(256) stats2(2) mbuf(128u) sbuf(128)
// total ~102.8 MB

__device__ __forceinline__ unsigned enc_f(float f) {
    unsigned u = __float_as_uint(f);
    return (u & 0x80000000u) ? ~u : (u | 0x80000000u);
}
__device__ __forceinline__ float dec_f(unsigned k) {
    unsigned u = (k & 0x80000000u) ? (k ^ 0x80000000u) : ~k;
    return __uint_as_float(u);
}

__global__ void k_init_small(float* sm) {
    int t = threadIdx.x;
    if (t < 770) sm[t] = 0.0f;
}

__global__ void k_zero(float4* p) {  // grid*256 == N*32 exactly
    int i = blockIdx.x * 256 + threadIdx.x;
    p[i] = make_float4(0.f, 0.f, 0.f, 0.f);
}

// one 32-lane group per edge; 4 floats/lane; atomic add into agg[dst]
__global__ void k_scatter(const float* __restrict__ x, const int* __restrict__ ei,
                          float* __restrict__ agg) {
    int t = blockIdx.x * 256 + threadIdx.x;
    int e = t >> 5, lane = t & 31;
    if (e >= EE) return;
    int s = ei[e], d = ei[EE + e];
    float4 v = ((const float4*)(x + (size_t)s * 128))[lane];
    float* b = agg + (size_t)d * 128 + lane * 4;
    unsafeAtomicAdd(b + 0, v.x);
    unsafeAtomicAdd(b + 1, v.y);
    unsafeAtomicAdd(b + 2, v.z);
    unsafeAtomicAdd(b + 3, v.w);
}

// Fused GIN MLP: reads (x + agg) tile -> LDS, gemm1(+bias,ReLU) -> mid in LDS,
// gemm2(+bias) -> write h in-place over agg buffer + BN-stat atomics.
// SECOND=false: write mid (post-ReLU) to aggh and stop (layer 2).
template <bool SECOND>
__global__ __launch_bounds__(256) void k_mlp(const float* __restrict__ x,
                                             float* __restrict__ aggh,
                                             const float* __restrict__ Wa,
                                             const float* __restrict__ ba,
                                             const float* __restrict__ Wb,
                                             const float* __restrict__ bb,
                                             float* __restrict__ stats) {
    __shared__ float As[64][132];
    __shared__ float Ws[32][132];
    const int t = threadIdx.x;
    const int row0 = blockIdx.x * 64;
    const int cg = t & 31, rg = t >> 5;
    const int c0 = cg * 4, r0 = rg * 8;

    // ---- phase 1: A tile = x + agg (OOB rows zeroed) ----
#pragma unroll
    for (int i = 0; i < 8; ++i) {
        int fidx = t + i * 256;
        int r = fidx >> 5, c4 = fidx & 31;
        int gr = row0 + r;
        float4 v = make_float4(0.f, 0.f, 0.f, 0.f);
        if (gr < NN) {
            float4 a = ((const float4*)(x + (size_t)gr * 128))[c4];
            float4 g = ((const float4*)(aggh + (size_t)gr * 128))[c4];
            v.x = a.x + g.x; v.y = a.y + g.y; v.z = a.z + g.z; v.w = a.w + g.w;
        }
        *(float4*)&As[r][c4 * 4] = v;
    }

    float acc[8][4];
#pragma unroll
    for (int i = 0; i < 8; ++i)
#pragma unroll
        for (int j = 0; j < 4; ++j) acc[i][j] = 0.f;

    // ---- gemm1: (x+agg) @ Wa ----
    for (int kc = 0; kc < 4; ++kc) {
#pragma unroll
        for (int i = 0; i < 4; ++i) {
            int widx = t + i * 256;
            int wr = widx >> 5, wc = (widx & 31) * 4;
            *(float4*)&Ws[wr][wc] = *(const float4*)&Wa[(kc * 32 + wr) * 128 + wc];
        }
        __syncthreads();
#pragma unroll
        for (int k = 0; k < 32; ++k) {
            float4 w = *(float4*)&Ws[k][c0];
#pragma unroll
            for (int i = 0; i < 8; ++i) {
                float a = As[r0 + i][kc * 32 + k];
                acc[i][0] = fmaf(a, w.x, acc[i][0]);
                acc[i][1] = fmaf(a, w.y, acc[i][1]);
                acc[i][2] = fmaf(a, w.z, acc[i][2]);
                acc[i][3] = fmaf(a, w.w, acc[i][3]);
            }
        }
        __syncthreads();
    }

    float4 bav = *(const float4*)&ba[c0];
    float mid[8][4];
#pragma unroll
    for (int i = 0; i < 8; ++i) {
        mid[i][0] = fmaxf(acc[i][0] + bav.x, 0.f);
        mid[i][1] = fmaxf(acc[i][1] + bav.y, 0.f);
        mid[i][2] = fmaxf(acc[i][2] + bav.z, 0.f);
        mid[i][3] = fmaxf(acc[i][3] + bav.w, 0.f);
    }

    if constexpr (!SECOND) {
#pragma unroll
        for (int i = 0; i < 8; ++i) {
            int gr = row0 + r0 + i;
            if (gr < NN)
                ((float4*)(aggh + (size_t)gr * 128))[cg] =
                    make_float4(mid[i][0], mid[i][1], mid[i][2], mid[i][3]);
        }
        return;
    } else {
        // mid -> LDS (As reuse; all reads of As finished at last barrier)
#pragma unroll
        for (int i = 0; i < 8; ++i)
            *(float4*)&As[r0 + i][c0] = make_float4(mid[i][0], mid[i][1], mid[i][2], mid[i][3]);
        __syncthreads();

#pragma unroll
        for (int i = 0; i < 8; ++i)
#pragma unroll
            for (int j = 0; j < 4; ++j) acc[i][j] = 0.f;

        for (int kc = 0; kc < 4; ++kc) {
#pragma unroll
            for (int i = 0; i < 4; ++i) {
                int widx = t + i * 256;
                int wr = widx >> 5, wc = (widx & 31) * 4;
                *(float4*)&Ws[wr][wc] = *(const float4*)&Wb[(kc * 32 + wr) * 128 + wc];
            }
            __syncthreads();
#pragma unroll
            for (int k = 0; k < 32; ++k) {
                float4 w = *(float4*)&Ws[k][c0];
#pragma unroll
                for (int i = 0; i < 8; ++i) {
                    float a = As[r0 + i][kc * 32 + k];
                    acc[i][0] = fmaf(a, w.x, acc[i][0]);
                    acc[i][1] = fmaf(a, w.y, acc[i][1]);
                    acc[i][2] = fmaf(a, w.z, acc[i][2]);
                    acc[i][3] = fmaf(a, w.w, acc[i][3]);
                }
            }
            __syncthreads();
        }

        float4 bbv = *(const float4*)&bb[c0];
        float s[4] = {0.f, 0.f, 0.f, 0.f}, ss[4] = {0.f, 0.f, 0.f, 0.f};
#pragma unroll
        for (int i = 0; i < 8; ++i) {
            int gr = row0 + r0 + i;
            float4 h = make_float4(acc[i][0] + bbv.x, acc[i][1] + bbv.y,
                                   acc[i][2] + bbv.z, acc[i][3] + bbv.w);
            if (gr < NN) {
                ((float4*)(aggh + (size_t)gr * 128))[cg] = h;
                s[0] += h.x; s[1] += h.y; s[2] += h.z; s[3] += h.w;
                ss[0] += h.x * h.x; ss[1] += h.y * h.y;
                ss[2] += h.z * h.z; ss[3] += h.w * h.w;
            }
        }
        // stats reduction in Ws scratch (4224 floats; need 2048)
        float* red = &Ws[0][0];
        *(float4*)&red[rg * 128 + c0] = make_float4(s[0], s[1], s[2], s[3]);
        *(float4*)&red[1024 + rg * 128 + c0] = make_float4(ss[0], ss[1], ss[2], ss[3]);
        __syncthreads();
        if (t < 128) {
            float v = 0.f;
#pragma unroll
            for (int r2 = 0; r2 < 8; ++r2) v += red[r2 * 128 + t];
            unsafeAtomicAdd(&stats[t], v);
        } else {
            int c = t - 128;
            float v = 0.f;
#pragma unroll
            for (int r2 = 0; r2 < 8; ++r2) v += red[1024 + r2 * 128 + c];
            unsafeAtomicAdd(&stats[128 + c], v);
        }
    }
}

__global__ void k_bn_relu(float* __restrict__ h, const float* __restrict__ stats,
                          const float* __restrict__ g, const float* __restrict__ be) {
    int i = blockIdx.x * 256 + threadIdx.x;  // float4 index, exactly N*32
    int c4 = i & 31;
    float4 sum = ((const float4*)stats)[c4];
    float4 ssq = ((const float4*)stats)[32 + c4];
    float4 gv = ((const float4*)g)[c4];
    float4 bev = ((const float4*)be)[c4];
    float4 v = ((float4*)h)[i];
    const float inv = 1.0f / (float)NN;
#define BN1(X, SU, SQ, GA, BE)                                   \
    {                                                            \
        float mu = (SU) * inv;                                   \
        float var = (SQ) * inv - mu * mu;                        \
        float sc = (GA) / sqrtf(var + BN_EPS);                   \
        float r = ((X) - mu) * sc + (BE);                        \
        (X) = fmaxf(r, 0.f);                                     \
    }
    BN1(v.x, sum.x, ssq.x, gv.x, bev.x)
    BN1(v.y, sum.y, ssq.y, gv.y, bev.y)
    BN1(v.z, sum.z, ssq.z, gv.z, bev.z)
    BN1(v.w, sum.w, ssq.w, gv.w, bev.w)
#undef BN1
    ((float4*)h)[i] = v;
}

// layer-2 second linear: z[n] = mid[n] . w + b  (+ BN(1) stats)
__global__ void k_dot(const float* __restrict__ mid, const float* __restrict__ w,
                      const float* __restrict__ b2, float* __restrict__ z,
                      float* __restrict__ s2) {
    __shared__ float rs[4], rss[4];
    int t = threadIdx.x, lane = t & 31, wg = t >> 5;
    float4 wv = ((const float4*)w)[lane];
    float bb = b2[0];
    float lsum = 0.f, lss = 0.f;
    int base = blockIdx.x * 64;
    for (int it = 0; it < 8; ++it) {
        int n = base + it * 8 + wg;
        float p = 0.f;
        if (n < NN) {
            float4 a = ((const float4*)(mid + (size_t)n * 128))[lane];
            p = a.x * wv.x + a.y * wv.y + a.z * wv.z + a.w * wv.w;
        }
#pragma unroll
        for (int off = 16; off > 0; off >>= 1) p += __shfl_xor(p, off, 32);
        float h2 = p + bb;
        if (n < NN && lane == 0) {
            z[n] = h2;
            lsum += h2;
            lss += h2 * h2;
        }
    }
#pragma unroll
    for (int off = 32; off > 0; off >>= 1) {
        lsum += __shfl_xor(lsum, off, 64);
        lss += __shfl_xor(lss, off, 64);
    }
    int wave = t >> 6;
    if ((t & 63) == 0) { rs[wave] = lsum; rss[wave] = lss; }
    __syncthreads();
    if (t == 0) {
        unsafeAtomicAdd(&s2[0], rs[0] + rs[1] + rs[2] + rs[3]);
        unsafeAtomicAdd(&s2[1], rss[0] + rss[1] + rss[2] + rss[3]);
    }
}

__global__ void k_bnz_max(const float* __restrict__ zr, const float* __restrict__ s2,
                          const float* __restrict__ g2, const float* __restrict__ be2,
                          const int* __restrict__ batch, float* __restrict__ out,
                          unsigned* __restrict__ mbuf) {
    int n = blockIdx.x * 256 + threadIdx.x;
    int nn = n < NN ? n : (NN - 1);
    float mu = s2[0] / (float)NN;
    float var = s2[1] / (float)NN - mu * mu;
    float sc = g2[0] / sqrtf(var + BN_EPS);
    float z = ((zr[nn] - mu) * sc + be2[0]) / 5.0f;
    int b = batch[nn];
    if (n < NN) out[n] = z;
    float zv = (n < NN) ? z : -INFINITY;
    int b0 = __shfl(b, 0, 64), b1 = __shfl(b, 63, 64);
    if (b0 == b1) {
#pragma unroll
        for (int off = 32; off > 0; off >>= 1) zv = fmaxf(zv, __shfl_xor(zv, off, 64));
        if ((threadIdx.x & 63) == 0) atomicMax(&mbuf[b0], enc_f(zv));
    } else if (n < NN) {
        atomicMax(&mbuf[b], enc_f(z));
    }
}

__global__ void k_expsum(float* __restrict__ out, const unsigned* __restrict__ mbuf,
                         const int* __restrict__ batch, float* __restrict__ sbuf) {
    int n = blockIdx.x * 256 + threadIdx.x;
    int nn = n < NN ? n : (NN - 1);
    int b = batch[nn];
    float z = out[nn];
    float e = expf(z - dec_f(mbuf[b]));
    if (n < NN) out[n] = e;
    float sv = (n < NN) ? e : 0.f;
    int b0 = __shfl(b, 0, 64), b1 = __shfl(b, 63, 64);
    if (b0 == b1) {
#pragma unroll
        for (int off = 32; off > 0; off >>= 1) sv += __shfl_xor(sv, off, 64);
        if ((threadIdx.x & 63) == 0) unsafeAtomicAdd(&sbuf[b0], sv);
    } else if (n < NN) {
        unsafeAtomicAdd(&sbuf[b], sv);
    }
}

__global__ void k_final(float* __restrict__ out, const float* __restrict__ sbuf,
                        const int* __restrict__ batch) {
    int n = blockIdx.x * 256 + threadIdx.x;
    if (n < NN) out[n] = out[n] / (sbuf[batch[n]] + 1e-16f);
}

extern "C" void kernel_launch(void* const* d_in, const int* in_sizes, int n_in,
                              void* d_out, int out_size, void* d_ws, size_t ws_size,
                              hipStream_t stream) {
    const float* x   = (const float*)d_in[0];
    const int* ei    = (const int*)d_in[1];
    const int* batch = (const int*)d_in[2];
    const float *W0a = (const float*)d_in[3],  *b0a = (const float*)d_in[4];
    const float *W0b = (const float*)d_in[5],  *b0b = (const float*)d_in[6];
    const float *g0  = (const float*)d_in[7],  *be0 = (const float*)d_in[8];
    const float *W1a = (const float*)d_in[9],  *b1a = (const float*)d_in[10];
    const float *W1b = (const float*)d_in[11], *b1b = (const float*)d_in[12];
    const float *g1  = (const float*)d_in[13], *be1 = (const float*)d_in[14];
    const float *W2a = (const float*)d_in[15], *b2a = (const float*)d_in[16];
    const float *W2b = (const float*)d_in[17], *b2b = (const float*)d_in[18];
    const float *g2  = (const float*)d_in[19], *be2 = (const float*)d_in[20];
    float* out = (float*)d_out;

    float* ws = (float*)d_ws;
    float* A  = ws;                       // N*128
    float* B  = ws + 12800000;            // N*128
    float* Z  = ws + 25600000;            // N
    float* SM = ws + 25700000;            // 770
    float* S0 = SM;
    float* S1 = SM + 256;
    float* S2 = SM + 512;
    unsigned* MB = (unsigned*)(SM + 514);
    float* SB = SM + 642;

    const int gZero = 12500;   // * 256 threads * float4 == N*128
    const int gScat = (EE * 32) / 256;    // 80000
    const int gMlp  = (NN + 63) / 64;     // 1563
    const int gSm   = (NN + 255) / 256;   // 391

    k_init_small<<<1, 1024, 0, stream>>>(SM);

    // layer 0
    k_zero<<<gZero, 256, 0, stream>>>((float4*)A);
    k_scatter<<<gScat, 256, 0, stream>>>(x, ei, A);
    k_mlp<true><<<gMlp, 256, 0, stream>>>(x, A, W0a, b0a, W0b, b0b, S0);
    k_bn_relu<<<gZero, 256, 0, stream>>>(A, S0, g0, be0);

    // layer 1
    k_zero<<<gZero, 256, 0, stream>>>((float4*)B);
    k_scatter<<<gScat, 256, 0, stream>>>(A, ei, B);
    k_mlp<true><<<gMlp, 256, 0, stream>>>(A, B, W1a, b1a, W1b, b1b, S1);
    k_bn_relu<<<gZero, 256, 0, stream>>>(B, S1, g1, be1);

    // layer 2
    k_zero<<<gZero, 256, 0, stream>>>((float4*)A);
    k_scatter<<<gScat, 256, 0, stream>>>(B, ei, A);
    k_mlp<false><<<gMlp, 256, 0, stream>>>(B, A, W2a, b2a, nullptr, nullptr, nullptr);
    k_dot<<<gMlp, 256, 0, stream>>>(A, W2b, b2b, Z, S2);

    // BN(1) + segment softmax (temperature 5)
    k_bnz_max<<<gSm, 256, 0, stream>>>(Z, S2, g2, be2, batch, out, MB);
    k_expsum<<<gSm, 256, 0, stream>>>(out, MB, batch, SB);
    k_final<<<gSm, 256, 0, stream>>>(out, SB, batch);
}

// Round 2
// 879.077 us; speedup vs baseline: 4.4303x; 4.4303x over previous
//
#include <hip/hip_runtime.h>
#include <math.h>

#define NN 100000
#define EE 640000
#define GG 128
#define BN_EPS 1e-5f
#define NBLK 98  // ceil(NN/1024)

// ---------------- ws layout (float offsets) ----------------
// A   : [0,          12,800,000)    N x 128
// B   : [12.8M,      25,600,000)    N x 128   (Z aliases B's head late in the pipe)
// SM  : [25,600,000, +770)          stats0(256) stats1(256) stats2(2) mbuf(128u) sbuf(128)
// INT : [25,600,800, ...) as int:   offs[N+1], bsums[128+pad], csr_src[E]
// deg/pos alias the A region during CSR build (A not yet live).

__device__ __forceinline__ unsigned enc_f(float f) {
    unsigned u = __float_as_uint(f);
    return (u & 0x80000000u) ? ~u : (u | 0x80000000u);
}
__device__ __forceinline__ float dec_f(unsigned k) {
    unsigned u = (k & 0x80000000u) ? (k ^ 0x80000000u) : ~k;
    return __uint_as_float(u);
}

__global__ void k_init_small(float* sm) {
    int t = threadIdx.x;
    if (t < 770) sm[t] = 0.0f;
}

__global__ void k_zero_i(int* p, int n) {
    int i = blockIdx.x * 256 + threadIdx.x;
    if (i < n) p[i] = 0;
}

// ---------------- CSR build ----------------
__global__ void k_hist(const int* __restrict__ ei, int* __restrict__ deg) {
    int e = blockIdx.x * 256 + threadIdx.x;
    if (e < EE) atomicAdd(&deg[ei[EE + e]], 1);
}

__global__ __launch_bounds__(1024) void k_scan1(const int* __restrict__ deg,
                                                int* __restrict__ offs,
                                                int* __restrict__ bsums) {
    __shared__ int sm[1024];
    int t = threadIdx.x;
    int i = blockIdx.x * 1024 + t;
    int v = (i < NN) ? deg[i] : 0;
    sm[t] = v;
    __syncthreads();
    for (int off = 1; off < 1024; off <<= 1) {
        int add = (t >= off) ? sm[t - off] : 0;
        __syncthreads();
        sm[t] += add;
        __syncthreads();
    }
    if (i < NN) offs[i] = sm[t] - v;  // exclusive within block
    if (t == 1023) bsums[blockIdx.x] = sm[1023];
}

__global__ void k_scan2(int* bsums) {
    if (threadIdx.x == 0 && blockIdx.x == 0) {
        int run = 0;
        for (int b = 0; b < NBLK; ++b) {
            int v = bsums[b];
            bsums[b] = run;
            run += v;
        }
    }
}

__global__ __launch_bounds__(1024) void k_scan3(int* __restrict__ offs,
                                                const int* __restrict__ bsums,
                                                int* __restrict__ pos) {
    int t = threadIdx.x;
    int i = blockIdx.x * 1024 + t;
    if (i < NN) {
        int o = offs[i] + bsums[blockIdx.x];
        offs[i] = o;
        pos[i] = o;
    }
    if (i == 0) offs[NN] = EE;
}

__global__ void k_fill(const int* __restrict__ ei, int* __restrict__ pos,
                       int* __restrict__ csr) {
    int e = blockIdx.x * 256 + threadIdx.x;
    if (e < EE) {
        int d = ei[EE + e];
        int p = atomicAdd(&pos[d], 1);
        csr[p] = ei[e];
    }
}

// agg[n] = x[n] + sum_{j in in(n)} x[src_j] ; one 32-lane group per node
__global__ void k_gather(const float* __restrict__ x, const int* __restrict__ offs,
                         const int* __restrict__ csr, float* __restrict__ agg) {
    int t = blockIdx.x * 256 + threadIdx.x;
    int n = t >> 5, lane = t & 31;
    if (n >= NN) return;
    int j0 = offs[n], j1 = offs[n + 1];
    float4 acc = ((const float4*)(x + (size_t)n * 128))[lane];
    for (int j = j0; j < j1; ++j) {
        int s = csr[j];
        float4 v = ((const float4*)(x + (size_t)s * 128))[lane];
        acc.x += v.x; acc.y += v.y; acc.z += v.z; acc.w += v.w;
    }
    ((float4*)(agg + (size_t)n * 128))[lane] = acc;
}

// ---------------- fallback-path helpers (ws too small for CSR) ----------------
__global__ void k_copy(const float4* __restrict__ in, float4* __restrict__ out) {
    int i = blockIdx.x * 256 + threadIdx.x;
    out[i] = in[i];
}

__global__ void k_scatter(const float* __restrict__ x, const int* __restrict__ ei,
                          float* __restrict__ agg) {
    int t = blockIdx.x * 256 + threadIdx.x;
    int e = t >> 5, lane = t & 31;
    if (e >= EE) return;
    int s = ei[e], d = ei[EE + e];
    float4 v = ((const float4*)(x + (size_t)s * 128))[lane];
    float* b = agg + (size_t)d * 128 + lane * 4;
    unsafeAtomicAdd(b + 0, v.x);
    unsafeAtomicAdd(b + 1, v.y);
    unsafeAtomicAdd(b + 2, v.z);
    unsafeAtomicAdd(b + 3, v.w);
}

// ---------------- fused GIN MLP ----------------
// Input h (= x + agg, combined). gemm1(+bias,ReLU) -> mid (LDS);
// SECOND: gemm2(+bias) -> write in place over h + BN-stat atomics.
// !SECOND: write mid (post-ReLU) in place and stop (layer 2).
template <bool SECOND>
__global__ __launch_bounds__(256) void k_mlp(float* __restrict__ h,
                                             const float* __restrict__ Wa,
                                             const float* __restrict__ ba,
                                             const float* __restrict__ Wb,
                                             const float* __restrict__ bb,
                                             float* __restrict__ stats) {
    __shared__ float As[64][132];
    __shared__ float Ws[32][132];
    const int t = threadIdx.x;
    const int row0 = blockIdx.x * 64;
    const int cg = t & 31, rg = t >> 5;
    const int c0 = cg * 4, r0 = rg * 8;

#pragma unroll
    for (int i = 0; i < 8; ++i) {
        int fidx = t + i * 256;
        int r = fidx >> 5, c4 = fidx & 31;
        int gr = row0 + r;
        float4 v = make_float4(0.f, 0.f, 0.f, 0.f);
        if (gr < NN) v = ((const float4*)(h + (size_t)gr * 128))[c4];
        *(float4*)&As[r][c4 * 4] = v;
    }

    float acc[8][4];
#pragma unroll
    for (int i = 0; i < 8; ++i)
#pragma unroll
        for (int j = 0; j < 4; ++j) acc[i][j] = 0.f;

    for (int kc = 0; kc < 4; ++kc) {
#pragma unroll
        for (int i = 0; i < 4; ++i) {
            int widx = t + i * 256;
            int wr = widx >> 5, wc = (widx & 31) * 4;
            *(float4*)&Ws[wr][wc] = *(const float4*)&Wa[(kc * 32 + wr) * 128 + wc];
        }
        __syncthreads();
#pragma unroll
        for (int k = 0; k < 32; ++k) {
            float4 w = *(float4*)&Ws[k][c0];
#pragma unroll
            for (int i = 0; i < 8; ++i) {
                float a = As[r0 + i][kc * 32 + k];
                acc[i][0] = fmaf(a, w.x, acc[i][0]);
                acc[i][1] = fmaf(a, w.y, acc[i][1]);
                acc[i][2] = fmaf(a, w.z, acc[i][2]);
                acc[i][3] = fmaf(a, w.w, acc[i][3]);
            }
        }
        __syncthreads();
    }

    float4 bav = *(const float4*)&ba[c0];
    float mid[8][4];
#pragma unroll
    for (int i = 0; i < 8; ++i) {
        mid[i][0] = fmaxf(acc[i][0] + bav.x, 0.f);
        mid[i][1] = fmaxf(acc[i][1] + bav.y, 0.f);
        mid[i][2] = fmaxf(acc[i][2] + bav.z, 0.f);
        mid[i][3] = fmaxf(acc[i][3] + bav.w, 0.f);
    }

    if constexpr (!SECOND) {
#pragma unroll
        for (int i = 0; i < 8; ++i) {
            int gr = row0 + r0 + i;
            if (gr < NN)
                ((float4*)(h + (size_t)gr * 128))[cg] =
                    make_float4(mid[i][0], mid[i][1], mid[i][2], mid[i][3]);
        }
        return;
    } else {
#pragma unroll
        for (int i = 0; i < 8; ++i)
            *(float4*)&As[r0 + i][c0] = make_float4(mid[i][0], mid[i][1], mid[i][2], mid[i][3]);
        __syncthreads();

#pragma unroll
        for (int i = 0; i < 8; ++i)
#pragma unroll
            for (int j = 0; j < 4; ++j) acc[i][j] = 0.f;

        for (int kc = 0; kc < 4; ++kc) {
#pragma unroll
            for (int i = 0; i < 4; ++i) {
                int widx = t + i * 256;
                int wr = widx >> 5, wc = (widx & 31) * 4;
                *(float4*)&Ws[wr][wc] = *(const float4*)&Wb[(kc * 32 + wr) * 128 + wc];
            }
            __syncthreads();
#pragma unroll
            for (int k = 0; k < 32; ++k) {
                float4 w = *(float4*)&Ws[k][c0];
#pragma unroll
                for (int i = 0; i < 8; ++i) {
                    float a = As[r0 + i][kc * 32 + k];
                    acc[i][0] = fmaf(a, w.x, acc[i][0]);
                    acc[i][1] = fmaf(a, w.y, acc[i][1]);
                    acc[i][2] = fmaf(a, w.z, acc[i][2]);
                    acc[i][3] = fmaf(a, w.w, acc[i][3]);
                }
            }
            __syncthreads();
        }

        float4 bbv = *(const float4*)&bb[c0];
        float s[4] = {0.f, 0.f, 0.f, 0.f}, ss[4] = {0.f, 0.f, 0.f, 0.f};
#pragma unroll
        for (int i = 0; i < 8; ++i) {
            int gr = row0 + r0 + i;
            float4 hv = make_float4(acc[i][0] + bbv.x, acc[i][1] + bbv.y,
                                    acc[i][2] + bbv.z, acc[i][3] + bbv.w);
            if (gr < NN) {
                ((float4*)(h + (size_t)gr * 128))[cg] = hv;
                s[0] += hv.x; s[1] += hv.y; s[2] += hv.z; s[3] += hv.w;
                ss[0] += hv.x * hv.x; ss[1] += hv.y * hv.y;
                ss[2] += hv.z * hv.z; ss[3] += hv.w * hv.w;
            }
        }
        float* red = &Ws[0][0];
        *(float4*)&red[rg * 128 + c0] = make_float4(s[0], s[1], s[2], s[3]);
        *(float4*)&red[1024 + rg * 128 + c0] = make_float4(ss[0], ss[1], ss[2], ss[3]);
        __syncthreads();
        if (t < 128) {
            float v = 0.f;
#pragma unroll
            for (int r2 = 0; r2 < 8; ++r2) v += red[r2 * 128 + t];
            unsafeAtomicAdd(&stats[t], v);
        } else {
            int c = t - 128;
            float v = 0.f;
#pragma unroll
            for (int r2 = 0; r2 < 8; ++r2) v += red[1024 + r2 * 128 + c];
            unsafeAtomicAdd(&stats[128 + c], v);
        }
    }
}

__global__ void k_bn_relu(float* __restrict__ h, const float* __restrict__ stats,
                          const float* __restrict__ g, const float* __restrict__ be) {
    int i = blockIdx.x * 256 + threadIdx.x;  // float4 index, exactly N*32
    int c4 = i & 31;
    float4 sum = ((const float4*)stats)[c4];
    float4 ssq = ((const float4*)stats)[32 + c4];
    float4 gv = ((const float4*)g)[c4];
    float4 bev = ((const float4*)be)[c4];
    float4 v = ((float4*)h)[i];
    const float inv = 1.0f / (float)NN;
#define BN1(X, SU, SQ, GA, BE)                                   \
    {                                                            \
        float mu = (SU) * inv;                                   \
        float var = (SQ) * inv - mu * mu;                        \
        float sc = (GA) / sqrtf(var + BN_EPS);                   \
        float r = ((X) - mu) * sc + (BE);                        \
        (X) = fmaxf(r, 0.f);                                     \
    }
    BN1(v.x, sum.x, ssq.x, gv.x, bev.x)
    BN1(v.y, sum.y, ssq.y, gv.y, bev.y)
    BN1(v.z, sum.z, ssq.z, gv.z, bev.z)
    BN1(v.w, sum.w, ssq.w, gv.w, bev.w)
#undef BN1
    ((float4*)h)[i] = v;
}

__global__ void k_dot(const float* __restrict__ mid, const float* __restrict__ w,
                      const float* __restrict__ b2, float* __restrict__ z,
                      float* __restrict__ s2) {
    __shared__ float rs[4], rss[4];
    int t = threadIdx.x, lane = t & 31, wg = t >> 5;
    float4 wv = ((const float4*)w)[lane];
    float bb = b2[0];
    float lsum = 0.f, lss = 0.f;
    int base = blockIdx.x * 64;
    for (int it = 0; it < 8; ++it) {
        int n = base + it * 8 + wg;
        float p = 0.f;
        if (n < NN) {
            float4 a = ((const float4*)(mid + (size_t)n * 128))[lane];
            p = a.x * wv.x + a.y * wv.y + a.z * wv.z + a.w * wv.w;
        }
#pragma unroll
        for (int off = 16; off > 0; off >>= 1) p += __shfl_xor(p, off, 32);
        float h2 = p + bb;
        if (n < NN && lane == 0) {
            z[n] = h2;
            lsum += h2;
            lss += h2 * h2;
        }
    }
#pragma unroll
    for (int off = 32; off > 0; off >>= 1) {
        lsum += __shfl_xor(lsum, off, 64);
        lss += __shfl_xor(lss, off, 64);
    }
    int wave = t >> 6;
    if ((t & 63) == 0) { rs[wave] = lsum; rss[wave] = lss; }
    __syncthreads();
    if (t == 0) {
        unsafeAtomicAdd(&s2[0], rs[0] + rs[1] + rs[2] + rs[3]);
        unsafeAtomicAdd(&s2[1], rss[0] + rss[1] + rss[2] + rss[3]);
    }
}

__global__ void k_bnz_max(const float* __restrict__ zr, const float* __restrict__ s2,
                          const float* __restrict__ g2, const float* __restrict__ be2,
                          const int* __restrict__ batch, float* __restrict__ out,
                          unsigned* __restrict__ mbuf) {
    int n = blockIdx.x * 256 + threadIdx.x;
    int nn = n < NN ? n : (NN - 1);
    float mu = s2[0] / (float)NN;
    float var = s2[1] / (float)NN - mu * mu;
    float sc = g2[0] / sqrtf(var + BN_EPS);
    float z = ((zr[nn] - mu) * sc + be2[0]) / 5.0f;
    int b = batch[nn];
    if (n < NN) out[n] = z;
    float zv = (n < NN) ? z : -INFINITY;
    int b0 = __shfl(b, 0, 64), b1 = __shfl(b, 63, 64);
    if (b0 == b1) {
#pragma unroll
        for (int off = 32; off > 0; off >>= 1) zv = fmaxf(zv, __shfl_xor(zv, off, 64));
        if ((threadIdx.x & 63) == 0) atomicMax(&mbuf[b0], enc_f(zv));
    } else if (n < NN) {
        atomicMax(&mbuf[b], enc_f(z));
    }
}

__global__ void k_expsum(float* __restrict__ out, const unsigned* __restrict__ mbuf,
                         const int* __restrict__ batch, float* __restrict__ sbuf) {
    int n = blockIdx.x * 256 + threadIdx.x;
    int nn = n < NN ? n : (NN - 1);
    int b = batch[nn];
    float z = out[nn];
    float e = expf(z - dec_f(mbuf[b]));
    if (n < NN) out[n] = e;
    float sv = (n < NN) ? e : 0.f;
    int b0 = __shfl(b, 0, 64), b1 = __shfl(b, 63, 64);
    if (b0 == b1) {
#pragma unroll
        for (int off = 32; off > 0; off >>= 1) sv += __shfl_xor(sv, off, 64);
        if ((threadIdx.x & 63) == 0) unsafeAtomicAdd(&sbuf[b0], sv);
    } else if (n < NN) {
        unsafeAtomicAdd(&sbuf[b], sv);
    }
}

__global__ void k_final(float* __restrict__ out, const float* __restrict__ sbuf,
                        const int* __restrict__ batch) {
    int n = blockIdx.x * 256 + threadIdx.x;
    if (n < NN) out[n] = out[n] / (sbuf[batch[n]] + 1e-16f);
}

extern "C" void kernel_launch(void* const* d_in, const int* in_sizes, int n_in,
                              void* d_out, int out_size, void* d_ws, size_t ws_size,
                              hipStream_t stream) {
    const float* x   = (const float*)d_in[0];
    const int* ei    = (const int*)d_in[1];
    const int* batch = (const int*)d_in[2];
    const float *W0a = (const float*)d_in[3],  *b0a = (const float*)d_in[4];
    const float *W0b = (const float*)d_in[5],  *b0b = (const float*)d_in[6];
    const float *g0  = (const float*)d_in[7],  *be0 = (const float*)d_in[8];
    const float *W1a = (const float*)d_in[9],  *b1a = (const float*)d_in[10];
    const float *W1b = (const float*)d_in[11], *b1b = (const float*)d_in[12];
    const float *g1  = (const float*)d_in[13], *be1 = (const float*)d_in[14];
    const float *W2a = (const float*)d_in[15], *b2a = (const float*)d_in[16];
    const float *W2b = (const float*)d_in[17], *b2b = (const float*)d_in[18];
    const float *g2  = (const float*)d_in[19], *be2 = (const float*)d_in[20];
    float* out = (float*)d_out;

    float* ws = (float*)d_ws;
    float* A  = ws;                    // N*128
    float* B  = ws + 12800000;         // N*128
    float* Z  = B;                     // aliases B head (B dead when Z is live)
    float* SM = ws + 25600000;         // 770 floats
    float* S0 = SM;
    float* S1 = SM + 256;
    float* S2 = SM + 512;
    unsigned* MB = (unsigned*)(SM + 514);
    float* SB = SM + 642;

    // CSR int region (beyond SM)
    int* IB   = (int*)(ws + 25600800);
    int* offs = IB;                    // N+1
    int* bsums = IB + 100002;          // 128
    int* csr  = IB + 100160;           // E
    const size_t need_bytes = (size_t)(25600800 + 100160 + EE) * 4;
    // deg/pos alias A region during CSR build (A not yet live)
    int* deg = (int*)ws;
    int* pos = (int*)ws + 131072;

    const int gE    = (EE + 255) / 256;        // 2500
    const int gN    = (NN + 255) / 256;        // 391
    const int gGat  = (NN * 32) / 256;         // 12500
    const int gMlp  = (NN + 63) / 64;          // 1563
    const int gCpy  = 12500;                   // * 256 * float4 == N*128

    k_init_small<<<1, 1024, 0, stream>>>(SM);

    if (ws_size >= need_bytes) {
        // ---- build CSR once (reused for all 3 layers) ----
        k_zero_i<<<gN, 256, 0, stream>>>(deg, NN);
        k_hist<<<gE, 256, 0, stream>>>(ei, deg);
        k_scan1<<<NBLK, 1024, 0, stream>>>(deg, offs, bsums);
        k_scan2<<<1, 64, 0, stream>>>(bsums);
        k_scan3<<<NBLK, 1024, 0, stream>>>(offs, bsums, pos);
        k_fill<<<gE, 256, 0, stream>>>(ei, pos, csr);

        // layer 0
        k_gather<<<gGat, 256, 0, stream>>>(x, offs, csr, A);
        k_mlp<true><<<gMlp, 256, 0, stream>>>(A, W0a, b0a, W0b, b0b, S0);
        k_bn_relu<<<gCpy, 256, 0, stream>>>(A, S0, g0, be0);
        // layer 1
        k_gather<<<gGat, 256, 0, stream>>>(A, offs, csr, B);
        k_mlp<true><<<gMlp, 256, 0, stream>>>(B, W1a, b1a, W1b, b1b, S1);
        k_bn_relu<<<gCpy, 256, 0, stream>>>(B, S1, g1, be1);
        // layer 2
        k_gather<<<gGat, 256, 0, stream>>>(B, offs, csr, A);
        k_mlp<false><<<gMlp, 256, 0, stream>>>(A, W2a, b2a, nullptr, nullptr, nullptr);
        k_dot<<<gMlp, 256, 0, stream>>>(A, W2b, b2b, Z, S2);
    } else {
        // ---- fallback: atomic scatter (init agg with x so agg = x + sum) ----
        k_copy<<<gCpy, 256, 0, stream>>>((const float4*)x, (float4*)A);
        k_scatter<<<(EE * 32) / 256, 256, 0, stream>>>(x, ei, A);
        k_mlp<true><<<gMlp, 256, 0, stream>>>(A, W0a, b0a, W0b, b0b, S0);
        k_bn_relu<<<gCpy, 256, 0, stream>>>(A, S0, g0, be0);

        k_copy<<<gCpy, 256, 0, stream>>>((const float4*)A, (float4*)B);
        k_scatter<<<(EE * 32) / 256, 256, 0, stream>>>(A, ei, B);
        k_mlp<true><<<gMlp, 256, 0, stream>>>(B, W1a, b1a, W1b, b1b, S1);
        k_bn_relu<<<gCpy, 256, 0, stream>>>(B, S1, g1, be1);

        k_copy<<<gCpy, 256, 0, stream>>>((const float4*)B, (float4*)A);
        k_scatter<<<(EE * 32) / 256, 256, 0, stream>>>(B, ei, A);
        k_mlp<false><<<gMlp, 256, 0, stream>>>(A, W2a, b2a, nullptr, nullptr, nullptr);
        k_dot<<<gMlp, 256, 0, stream>>>(A, W2b, b2b, Z, S2);
    }

    // BN(1) + segment softmax (temperature 5)
    k_bnz_max<<<gN, 256, 0, stream>>>(Z, S2, g2, be2, batch, out, MB);
    k_expsum<<<gN, 256, 0, stream>>>(out, MB, batch, SB);
    k_final<<<gN, 256, 0, stream>>>(out, SB, batch);
}

// Round 3
// 722.834 us; speedup vs baseline: 5.3879x; 1.2162x over previous
//
#include <hip/hip_runtime.h>
#include <math.h>

#define NN 100000
#define EE 640000
#define GG 128
#define BN_EPS 1e-5f
#define NBLK 98  // ceil(NN/1024)

// ---------------- ws layout (float offsets) ----------------
// A   : [0,          12,800,000)    N x 128
// B   : [12.8M,      25,600,000)    N x 128   (Z aliases B's head late in the pipe)
// SM  : [25,600,000, +1536)         S0(256) S1(256) S2(2) MB(128) SB(128) pad P0(256) P1(256)
// INT : [25,602,048, ...) as int:   offs[N+1], bsums[128+pad], csr_src[E]
// deg/pos alias the A region during CSR build (A not yet live).

__device__ __forceinline__ unsigned enc_f(float f) {
    unsigned u = __float_as_uint(f);
    return (u & 0x80000000u) ? ~u : (u | 0x80000000u);
}
__device__ __forceinline__ float dec_f(unsigned k) {
    unsigned u = (k & 0x80000000u) ? (k ^ 0x80000000u) : ~k;
    return __uint_as_float(u);
}

__global__ void k_init_small(float* sm) {
    int t = threadIdx.x;
    if (t < 770) sm[t] = 0.0f;
}

__global__ void k_zero_i(int* p, int n) {
    int i = blockIdx.x * 256 + threadIdx.x;
    if (i < n) p[i] = 0;
}

// ---------------- CSR build ----------------
__global__ void k_hist(const int* __restrict__ ei, int* __restrict__ deg) {
    int e = blockIdx.x * 256 + threadIdx.x;
    if (e < EE) atomicAdd(&deg[ei[EE + e]], 1);
}

__global__ __launch_bounds__(1024) void k_scan1(const int* __restrict__ deg,
                                                int* __restrict__ offs,
                                                int* __restrict__ bsums) {
    __shared__ int sm[1024];
    int t = threadIdx.x;
    int i = blockIdx.x * 1024 + t;
    int v = (i < NN) ? deg[i] : 0;
    sm[t] = v;
    __syncthreads();
    for (int off = 1; off < 1024; off <<= 1) {
        int add = (t >= off) ? sm[t - off] : 0;
        __syncthreads();
        sm[t] += add;
        __syncthreads();
    }
    if (i < NN) offs[i] = sm[t] - v;  // exclusive within block
    if (t == 1023) bsums[blockIdx.x] = sm[1023];
}

__global__ void k_scan2(int* bsums) {
    __shared__ int sm[128];
    int t = threadIdx.x;
    int v = (t < NBLK) ? bsums[t] : 0;
    sm[t] = v;
    __syncthreads();
    for (int off = 1; off < 128; off <<= 1) {
        int add = (t >= off) ? sm[t - off] : 0;
        __syncthreads();
        sm[t] += add;
        __syncthreads();
    }
    if (t < NBLK) bsums[t] = sm[t] - v;  // exclusive
}

__global__ __launch_bounds__(1024) void k_scan3(int* __restrict__ offs,
                                                const int* __restrict__ bsums,
                                                int* __restrict__ pos) {
    int t = threadIdx.x;
    int i = blockIdx.x * 1024 + t;
    if (i < NN) {
        int o = offs[i] + bsums[blockIdx.x];
        offs[i] = o;
        pos[i] = o;
    }
    if (i == 0) offs[NN] = EE;
}

__global__ void k_fill(const int* __restrict__ ei, int* __restrict__ pos,
                       int* __restrict__ csr) {
    int e = blockIdx.x * 256 + threadIdx.x;
    if (e < EE) {
        int d = ei[EE + e];
        int p = atomicAdd(&pos[d], 1);
        csr[p] = ei[e];
    }
}

// BN scale/shift precompute: sc = g/sqrt(var+eps), sh = be - mu*sc
__global__ void k_bnpar(const float* __restrict__ stats, const float* __restrict__ g,
                        const float* __restrict__ be, float* __restrict__ par) {
    int c = threadIdx.x;  // 128
    const float inv = 1.0f / (float)NN;
    float mu = stats[c] * inv;
    float var = stats[128 + c] * inv - mu * mu;
    float sc = g[c] / sqrtf(var + BN_EPS);
    par[c] = sc;
    par[128 + c] = be[c] - mu * sc;
}

// agg[n] = sum_{j in in(n) U {n}} f(x[j]) where f = identity or relu(bn(.))
// one 32-lane group per node
template <bool BN>
__global__ void k_gather(const float* __restrict__ x, const int* __restrict__ offs,
                         const int* __restrict__ csr, const float* __restrict__ par,
                         float* __restrict__ agg) {
    int t = blockIdx.x * 256 + threadIdx.x;
    int n = t >> 5, lane = t & 31;
    if (n >= NN) return;
    float4 scv, shv;
    if constexpr (BN) {
        scv = ((const float4*)par)[lane];
        shv = ((const float4*)(par + 128))[lane];
    }
    int j0 = offs[n], j1 = offs[n + 1];
    float4 v = ((const float4*)(x + (size_t)n * 128))[lane];
    float4 acc;
    if constexpr (BN) {
        acc.x = fmaxf(fmaf(v.x, scv.x, shv.x), 0.f);
        acc.y = fmaxf(fmaf(v.y, scv.y, shv.y), 0.f);
        acc.z = fmaxf(fmaf(v.z, scv.z, shv.z), 0.f);
        acc.w = fmaxf(fmaf(v.w, scv.w, shv.w), 0.f);
    } else {
        acc = v;
    }
    int s_next = (j0 < j1) ? csr[j0] : 0;
    for (int j = j0; j < j1; ++j) {
        int s = s_next;
        if (j + 1 < j1) s_next = csr[j + 1];
        float4 w = ((const float4*)(x + (size_t)s * 128))[lane];
        if constexpr (BN) {
            acc.x += fmaxf(fmaf(w.x, scv.x, shv.x), 0.f);
            acc.y += fmaxf(fmaf(w.y, scv.y, shv.y), 0.f);
            acc.z += fmaxf(fmaf(w.z, scv.z, shv.z), 0.f);
            acc.w += fmaxf(fmaf(w.w, scv.w, shv.w), 0.f);
        } else {
            acc.x += w.x; acc.y += w.y; acc.z += w.z; acc.w += w.w;
        }
    }
    ((float4*)(agg + (size_t)n * 128))[lane] = acc;
}

// ---------------- fused GIN MLP ----------------
// Input h (= combined x+agg). gemm1(+bias,ReLU) -> mid (LDS);
// SECOND: gemm2(+bias) -> write in place over h + BN-stat atomics.
// !SECOND: write mid (post-ReLU) in place and stop (layer 2).
template <bool SECOND>
__global__ __launch_bounds__(256, 3) void k_mlp(float* __restrict__ h,
                                                const float* __restrict__ Wa,
                                                const float* __restrict__ ba,
                                                const float* __restrict__ Wb,
                                                const float* __restrict__ bb,
                                                float* __restrict__ stats) {
    __shared__ float As[64][132];
    __shared__ float Ws[32][132];
    const int t = threadIdx.x;
    const int row0 = blockIdx.x * 64;
    const int cg = t & 31, rg = t >> 5;
    const int c0 = cg * 4, r0 = rg * 8;

#pragma unroll
    for (int i = 0; i < 8; ++i) {
        int fidx = t + i * 256;
        int r = fidx >> 5, c4 = fidx & 31;
        int gr = row0 + r;
        float4 v = make_float4(0.f, 0.f, 0.f, 0.f);
        if (gr < NN) v = ((const float4*)(h + (size_t)gr * 128))[c4];
        *(float4*)&As[r][c4 * 4] = v;
    }

    float acc[8][4];
#pragma unroll
    for (int i = 0; i < 8; ++i)
#pragma unroll
        for (int j = 0; j < 4; ++j) acc[i][j] = 0.f;

    // macro: one k-substep (component JP of the a-frags against W row k4*4+JP)
#define MLP_STEP(JP, COMP)                                          \
    {                                                               \
        float4 w = *(float4*)&Ws[k4 * 4 + JP][c0];                  \
        _Pragma("unroll") for (int i = 0; i < 8; ++i) {             \
            float av = a[i].COMP;                                   \
            acc[i][0] = fmaf(av, w.x, acc[i][0]);                   \
            acc[i][1] = fmaf(av, w.y, acc[i][1]);                   \
            acc[i][2] = fmaf(av, w.z, acc[i][2]);                   \
            acc[i][3] = fmaf(av, w.w, acc[i][3]);                   \
        }                                                           \
    }

#define MLP_GEMM(WPTR)                                                        \
    for (int kc = 0; kc < 4; ++kc) {                                          \
        _Pragma("unroll") for (int i = 0; i < 4; ++i) {                       \
            int widx = t + i * 256;                                           \
            int wr = widx >> 5, wc = (widx & 31) * 4;                         \
            *(float4*)&Ws[wr][wc] = *(const float4*)&WPTR[(kc * 32 + wr) * 128 + wc]; \
        }                                                                     \
        __syncthreads();                                                      \
        _Pragma("unroll") for (int k4 = 0; k4 < 8; ++k4) {                    \
            float4 a[8];                                                      \
            _Pragma("unroll") for (int i = 0; i < 8; ++i)                     \
                a[i] = *(float4*)&As[r0 + i][kc * 32 + k4 * 4];               \
            MLP_STEP(0, x)                                                    \
            MLP_STEP(1, y)                                                    \
            MLP_STEP(2, z)                                                    \
            MLP_STEP(3, w)                                                    \
        }                                                                     \
        __syncthreads();                                                      \
    }

    MLP_GEMM(Wa)

    float4 bav = *(const float4*)&ba[c0];
    float mid[8][4];
#pragma unroll
    for (int i = 0; i < 8; ++i) {
        mid[i][0] = fmaxf(acc[i][0] + bav.x, 0.f);
        mid[i][1] = fmaxf(acc[i][1] + bav.y, 0.f);
        mid[i][2] = fmaxf(acc[i][2] + bav.z, 0.f);
        mid[i][3] = fmaxf(acc[i][3] + bav.w, 0.f);
    }

    if constexpr (!SECOND) {
#pragma unroll
        for (int i = 0; i < 8; ++i) {
            int gr = row0 + r0 + i;
            if (gr < NN)
                ((float4*)(h + (size_t)gr * 128))[cg] =
                    make_float4(mid[i][0], mid[i][1], mid[i][2], mid[i][3]);
        }
        return;
    } else {
#pragma unroll
        for (int i = 0; i < 8; ++i)
            *(float4*)&As[r0 + i][c0] = make_float4(mid[i][0], mid[i][1], mid[i][2], mid[i][3]);
        __syncthreads();

#pragma unroll
        for (int i = 0; i < 8; ++i)
#pragma unroll
            for (int j = 0; j < 4; ++j) acc[i][j] = 0.f;

        MLP_GEMM(Wb)

        float4 bbv = *(const float4*)&bb[c0];
        float s[4] = {0.f, 0.f, 0.f, 0.f}, ss[4] = {0.f, 0.f, 0.f, 0.f};
#pragma unroll
        for (int i = 0; i < 8; ++i) {
            int gr = row0 + r0 + i;
            float4 hv = make_float4(acc[i][0] + bbv.x, acc[i][1] + bbv.y,
                                    acc[i][2] + bbv.z, acc[i][3] + bbv.w);
            if (gr < NN) {
                ((float4*)(h + (size_t)gr * 128))[cg] = hv;
                s[0] += hv.x; s[1] += hv.y; s[2] += hv.z; s[3] += hv.w;
                ss[0] += hv.x * hv.x; ss[1] += hv.y * hv.y;
                ss[2] += hv.z * hv.z; ss[3] += hv.w * hv.w;
            }
        }
        float* red = &Ws[0][0];
        *(float4*)&red[rg * 128 + c0] = make_float4(s[0], s[1], s[2], s[3]);
        *(float4*)&red[1024 + rg * 128 + c0] = make_float4(ss[0], ss[1], ss[2], ss[3]);
        __syncthreads();
        if (t < 128) {
            float v = 0.f;
#pragma unroll
            for (int r2 = 0; r2 < 8; ++r2) v += red[r2 * 128 + t];
            unsafeAtomicAdd(&stats[t], v);
        } else {
            int c = t - 128;
            float v = 0.f;
#pragma unroll
            for (int r2 = 0; r2 < 8; ++r2) v += red[1024 + r2 * 128 + c];
            unsafeAtomicAdd(&stats[128 + c], v);
        }
    }
#undef MLP_GEMM
#undef MLP_STEP
}

__global__ void k_dot(const float* __restrict__ mid, const float* __restrict__ w,
                      const float* __restrict__ b2, float* __restrict__ z,
                      float* __restrict__ s2) {
    __shared__ float rs[4], rss[4];
    int t = threadIdx.x, lane = t & 31, wg = t >> 5;
    float4 wv = ((const float4*)w)[lane];
    float bb = b2[0];
    float lsum = 0.f, lss = 0.f;
    int base = blockIdx.x * 64;
    for (int it = 0; it < 8; ++it) {
        int n = base + it * 8 + wg;
        float p = 0.f;
        if (n < NN) {
            float4 a = ((const float4*)(mid + (size_t)n * 128))[lane];
            p = a.x * wv.x + a.y * wv.y + a.z * wv.z + a.w * wv.w;
        }
#pragma unroll
        for (int off = 16; off > 0; off >>= 1) p += __shfl_xor(p, off, 32);
        float h2 = p + bb;
        if (n < NN && lane == 0) {
            z[n] = h2;
            lsum += h2;
            lss += h2 * h2;
        }
    }
#pragma unroll
    for (int off = 32; off > 0; off >>= 1) {
        lsum += __shfl_xor(lsum, off, 64);
        lss += __shfl_xor(lss, off, 64);
    }
    int wave = t >> 6;
    if ((t & 63) == 0) { rs[wave] = lsum; rss[wave] = lss; }
    __syncthreads();
    if (t == 0) {
        unsafeAtomicAdd(&s2[0], rs[0] + rs[1] + rs[2] + rs[3]);
        unsafeAtomicAdd(&s2[1], rss[0] + rss[1] + rss[2] + rss[3]);
    }
}

__global__ void k_bnz_max(const float* __restrict__ zr, const float* __restrict__ s2,
                          const float* __restrict__ g2, const float* __restrict__ be2,
                          const int* __restrict__ batch, float* __restrict__ out,
                          unsigned* __restrict__ mbuf) {
    int n = blockIdx.x * 256 + threadIdx.x;
    int nn = n < NN ? n : (NN - 1);
    float mu = s2[0] / (float)NN;
    float var = s2[1] / (float)NN - mu * mu;
    float sc = g2[0] / sqrtf(var + BN_EPS);
    float z = ((zr[nn] - mu) * sc + be2[0]) / 5.0f;
    int b = batch[nn];
    if (n < NN) out[n] = z;
    float zv = (n < NN) ? z : -INFINITY;
    int b0 = __shfl(b, 0, 64), b1 = __shfl(b, 63, 64);
    if (b0 == b1) {
#pragma unroll
        for (int off = 32; off > 0; off >>= 1) zv = fmaxf(zv, __shfl_xor(zv, off, 64));
        if ((threadIdx.x & 63) == 0) atomicMax(&mbuf[b0], enc_f(zv));
    } else if (n < NN) {
        atomicMax(&mbuf[b], enc_f(z));
    }
}

__global__ void k_expsum(float* __restrict__ out, const unsigned* __restrict__ mbuf,
                         const int* __restrict__ batch, float* __restrict__ sbuf) {
    int n = blockIdx.x * 256 + threadIdx.x;
    int nn = n < NN ? n : (NN - 1);
    int b = batch[nn];
    float z = out[nn];
    float e = expf(z - dec_f(mbuf[b]));
    if (n < NN) out[n] = e;
    float sv = (n < NN) ? e : 0.f;
    int b0 = __shfl(b, 0, 64), b1 = __shfl(b, 63, 64);
    if (b0 == b1) {
#pragma unroll
        for (int off = 32; off > 0; off >>= 1) sv += __shfl_xor(sv, off, 64);
        if ((threadIdx.x & 63) == 0) unsafeAtomicAdd(&sbuf[b0], sv);
    } else if (n < NN) {
        unsafeAtomicAdd(&sbuf[b], sv);
    }
}

__global__ void k_final(float* __restrict__ out, const float* __restrict__ sbuf,
                        const int* __restrict__ batch) {
    int n = blockIdx.x * 256 + threadIdx.x;
    if (n < NN) out[n] = out[n] / (sbuf[batch[n]] + 1e-16f);
}

// ---------------- fallback-path helpers (ws too small for CSR) ----------------
__global__ void k_copy(const float4* __restrict__ in, float4* __restrict__ out) {
    int i = blockIdx.x * 256 + threadIdx.x;
    out[i] = in[i];
}

__global__ void k_scatter(const float* __restrict__ x, const int* __restrict__ ei,
                          float* __restrict__ agg) {
    int t = blockIdx.x * 256 + threadIdx.x;
    int e = t >> 5, lane = t & 31;
    if (e >= EE) return;
    int s = ei[e], d = ei[EE + e];
    float4 v = ((const float4*)(x + (size_t)s * 128))[lane];
    float* b = agg + (size_t)d * 128 + lane * 4;
    unsafeAtomicAdd(b + 0, v.x);
    unsafeAtomicAdd(b + 1, v.y);
    unsafeAtomicAdd(b + 2, v.z);
    unsafeAtomicAdd(b + 3, v.w);
}

__global__ void k_bn_relu(float* __restrict__ h, const float* __restrict__ stats,
                          const float* __restrict__ g, const float* __restrict__ be) {
    int i = blockIdx.x * 256 + threadIdx.x;
    int c4 = i & 31;
    float4 sum = ((const float4*)stats)[c4];
    float4 ssq = ((const float4*)stats)[32 + c4];
    float4 gv = ((const float4*)g)[c4];
    float4 bev = ((const float4*)be)[c4];
    float4 v = ((float4*)h)[i];
    const float inv = 1.0f / (float)NN;
#define BN1(X, SU, SQ, GA, BE)                                   \
    {                                                            \
        float mu = (SU) * inv;                                   \
        float var = (SQ) * inv - mu * mu;                        \
        float sc = (GA) / sqrtf(var + BN_EPS);                   \
        float r = ((X) - mu) * sc + (BE);                        \
        (X) = fmaxf(r, 0.f);                                     \
    }
    BN1(v.x, sum.x, ssq.x, gv.x, bev.x)
    BN1(v.y, sum.y, ssq.y, gv.y, bev.y)
    BN1(v.z, sum.z, ssq.z, gv.z, bev.z)
    BN1(v.w, sum.w, ssq.w, gv.w, bev.w)
#undef BN1
    ((float4*)h)[i] = v;
}

extern "C" void kernel_launch(void* const* d_in, const int* in_sizes, int n_in,
                              void* d_out, int out_size, void* d_ws, size_t ws_size,
                              hipStream_t stream) {
    const float* x   = (const float*)d_in[0];
    const int* ei    = (const int*)d_in[1];
    const int* batch = (const int*)d_in[2];
    const float *W0a = (const float*)d_in[3],  *b0a = (const float*)d_in[4];
    const float *W0b = (const float*)d_in[5],  *b0b = (const float*)d_in[6];
    const float *g0  = (const float*)d_in[7],  *be0 = (const float*)d_in[8];
    const float *W1a = (const float*)d_in[9],  *b1a = (const float*)d_in[10];
    const float *W1b = (const float*)d_in[11], *b1b = (const float*)d_in[12];
    const float *g1  = (const float*)d_in[13], *be1 = (const float*)d_in[14];
    const float *W2a = (const float*)d_in[15], *b2a = (const float*)d_in[16];
    const float *W2b = (const float*)d_in[17], *b2b = (const float*)d_in[18];
    const float *g2  = (const float*)d_in[19], *be2 = (const float*)d_in[20];
    float* out = (float*)d_out;

    float* ws = (float*)d_ws;
    float* A  = ws;                    // N*128
    float* B  = ws + 12800000;         // N*128
    float* Z  = B;                     // aliases B head (B dead when Z is live)
    float* SM = ws + 25600000;         // 1536 floats
    float* S0 = SM;
    float* S1 = SM + 256;
    float* S2 = SM + 512;
    unsigned* MB = (unsigned*)(SM + 514);
    float* SB = SM + 642;
    float* P0 = SM + 896;              // sc0(128) sh0(128)
    float* P1 = SM + 1152;             // sc1(128) sh1(128)

    // CSR int region (beyond SM)
    int* IB   = (int*)(ws + 25602048);
    int* offs = IB;                    // N+1
    int* bsums = IB + 100002;          // 128
    int* csr  = IB + 100160;           // E
    const size_t need_bytes = (size_t)(25602048 + 100160 + EE) * 4;
    // deg/pos alias A region during CSR build (A not yet live)
    int* deg = (int*)ws;
    int* pos = (int*)ws + 131072;

    const int gE    = (EE + 255) / 256;        // 2500
    const int gN    = (NN + 255) / 256;        // 391
    const int gGat  = (NN * 32) / 256;         // 12500
    const int gMlp  = (NN + 63) / 64;          // 1563
    const int gCpy  = 12500;                   // * 256 * float4 == N*128

    k_init_small<<<1, 1024, 0, stream>>>(SM);

    if (ws_size >= need_bytes) {
        // ---- build CSR once (reused for all 3 layers) ----
        k_zero_i<<<gN, 256, 0, stream>>>(deg, NN);
        k_hist<<<gE, 256, 0, stream>>>(ei, deg);
        k_scan1<<<NBLK, 1024, 0, stream>>>(deg, offs, bsums);
        k_scan2<<<1, 128, 0, stream>>>(bsums);
        k_scan3<<<NBLK, 1024, 0, stream>>>(offs, bsums, pos);
        k_fill<<<gE, 256, 0, stream>>>(ei, pos, csr);

        // layer 0
        k_gather<false><<<gGat, 256, 0, stream>>>(x, offs, csr, nullptr, A);
        k_mlp<true><<<gMlp, 256, 0, stream>>>(A, W0a, b0a, W0b, b0b, S0);
        k_bnpar<<<1, 128, 0, stream>>>(S0, g0, be0, P0);
        // layer 1 (BN0+ReLU fused into gather)
        k_gather<true><<<gGat, 256, 0, stream>>>(A, offs, csr, P0, B);
        k_mlp<true><<<gMlp, 256, 0, stream>>>(B, W1a, b1a, W1b, b1b, S1);
        k_bnpar<<<1, 128, 0, stream>>>(S1, g1, be1, P1);
        // layer 2 (BN1+ReLU fused into gather)
        k_gather<true><<<gGat, 256, 0, stream>>>(B, offs, csr, P1, A);
        k_mlp<false><<<gMlp, 256, 0, stream>>>(A, W2a, b2a, nullptr, nullptr, nullptr);
        k_dot<<<gMlp, 256, 0, stream>>>(A, W2b, b2b, Z, S2);
    } else {
        // ---- fallback: atomic scatter path ----
        k_copy<<<gCpy, 256, 0, stream>>>((const float4*)x, (float4*)A);
        k_scatter<<<(EE * 32) / 256, 256, 0, stream>>>(x, ei, A);
        k_mlp<true><<<gMlp, 256, 0, stream>>>(A, W0a, b0a, W0b, b0b, S0);
        k_bn_relu<<<gCpy, 256, 0, stream>>>(A, S0, g0, be0);

        k_copy<<<gCpy, 256, 0, stream>>>((const float4*)A, (float4*)B);
        k_scatter<<<(EE * 32) / 256, 256, 0, stream>>>(A, ei, B);
        k_mlp<true><<<gMlp, 256, 0, stream>>>(B, W1a, b1a, W1b, b1b, S1);
        k_bn_relu<<<gCpy, 256, 0, stream>>>(B, S1, g1, be1);

        k_copy<<<gCpy, 256, 0, stream>>>((const float4*)B, (float4*)A);
        k_scatter<<<(EE * 32) / 256, 256, 0, stream>>>(B, ei, A);
        k_mlp<false><<<gMlp, 256, 0, stream>>>(A, W2a, b2a, nullptr, nullptr, nullptr);
        k_dot<<<gMlp, 256, 0, stream>>>(A, W2b, b2b, Z, S2);
    }

    // BN(1) + segment softmax (temperature 5)
    k_bnz_max<<<gN, 256, 0, stream>>>(Z, S2, g2, be2, batch, out, MB);
    k_expsum<<<gN, 256, 0, stream>>>(out, MB, batch, SB);
    k_final<<<gN, 256, 0, stream>>>(out, SB, batch);
}

// Round 4
// 650.071 us; speedup vs baseline: 5.9909x; 1.1119x over previous
//
#include <hip/hip_runtime.h>
#include <math.h>

#define NN 100000
#define EE 640000
#define GG 128
#define BN_EPS 1e-5f
#define NBLK 98  // ceil(NN/1024)

typedef __attribute__((ext_vector_type(8))) short short8;
typedef __attribute__((ext_vector_type(4))) float f32x4;

// ---------------- ws layout (byte offsets) ----------------
// Abf : [0,          25,600,000)   N x 128 bf16
// Bbf : [25.6M,      51,200,000)   N x 128 bf16
// Z   : [51,200,000, +400,000)     N fp32
// SM  : [51,600,000, +6,144)       S0(256) S1(256) S2(2) MB(128) SB(128) pad P0(256) P1(256)
// offs: [51,606,144, +400,004)     N+1 int
// bsum: [52,006,148, +512)
// csr : [52,006,660, +2,560,000)
// Wt  : [54,566,672, +163,840)     5 x 128x128 bf16 (transposed weights)
// deg/pos alias Abf region during CSR build (Abf not yet live).

__device__ __forceinline__ unsigned enc_f(float f) {
    unsigned u = __float_as_uint(f);
    return (u & 0x80000000u) ? ~u : (u | 0x80000000u);
}
__device__ __forceinline__ float dec_f(unsigned k) {
    unsigned u = (k & 0x80000000u) ? (k ^ 0x80000000u) : ~k;
    return __uint_as_float(u);
}
__device__ __forceinline__ short f2bf(float f) {
    unsigned u = __float_as_uint(f);
    u += 0x7fffu + ((u >> 16) & 1);
    return (short)(u >> 16);
}
__device__ __forceinline__ float bf2f(short s) {
    return __uint_as_float(((unsigned)(unsigned short)s) << 16);
}

__global__ void k_init_small(float* sm) {
    int t = threadIdx.x;
    if (t < 770) sm[t] = 0.0f;
}

__global__ void k_zero_i(int* p, int n) {
    int i = blockIdx.x * 256 + threadIdx.x;
    if (i < n) p[i] = 0;
}

// W (fp32 [k][n]) -> Wt (bf16 [n][k]) for 5 weights
__global__ void k_prepw(const float* __restrict__ W0a, const float* __restrict__ W0b,
                        const float* __restrict__ W1a, const float* __restrict__ W1b,
                        const float* __restrict__ W2a, short* __restrict__ Wt) {
    int idx = blockIdx.x * 256 + threadIdx.x;  // 5*16384
    int wi = idx >> 14, r = idx & 16383;
    const float* W = (wi == 0) ? W0a : (wi == 1) ? W0b : (wi == 2) ? W1a
                    : (wi == 3) ? W1b : W2a;
    int k = r >> 7, n = r & 127;
    Wt[wi * 16384 + n * 128 + k] = f2bf(W[k * 128 + n]);
}

// ---------------- CSR build ----------------
__global__ void k_hist(const int* __restrict__ ei, int* __restrict__ deg) {
    int e = blockIdx.x * 256 + threadIdx.x;
    if (e < EE) atomicAdd(&deg[ei[EE + e]], 1);
}

__global__ __launch_bounds__(1024) void k_scan1(const int* __restrict__ deg,
                                                int* __restrict__ offs,
                                                int* __restrict__ bsums) {
    __shared__ int sm[1024];
    int t = threadIdx.x;
    int i = blockIdx.x * 1024 + t;
    int v = (i < NN) ? deg[i] : 0;
    sm[t] = v;
    __syncthreads();
    for (int off = 1; off < 1024; off <<= 1) {
        int add = (t >= off) ? sm[t - off] : 0;
        __syncthreads();
        sm[t] += add;
        __syncthreads();
    }
    if (i < NN) offs[i] = sm[t] - v;
    if (t == 1023) bsums[blockIdx.x] = sm[1023];
}

__global__ void k_scan2(int* bsums) {
    __shared__ int sm[128];
    int t = threadIdx.x;
    int v = (t < NBLK) ? bsums[t] : 0;
    sm[t] = v;
    __syncthreads();
    for (int off = 1; off < 128; off <<= 1) {
        int add = (t >= off) ? sm[t - off] : 0;
        __syncthreads();
        sm[t] += add;
        __syncthreads();
    }
    if (t < NBLK) bsums[t] = sm[t] - v;
}

__global__ __launch_bounds__(1024) void k_scan3(int* __restrict__ offs,
                                                const int* __restrict__ bsums,
                                                int* __restrict__ pos) {
    int t = threadIdx.x;
    int i = blockIdx.x * 1024 + t;
    if (i < NN) {
        int o = offs[i] + bsums[blockIdx.x];
        offs[i] = o;
        pos[i] = o;
    }
    if (i == 0) offs[NN] = EE;
}

__global__ void k_fill(const int* __restrict__ ei, int* __restrict__ pos,
                       int* __restrict__ csr) {
    int e = blockIdx.x * 256 + threadIdx.x;
    if (e < EE) {
        int d = ei[EE + e];
        int p = atomicAdd(&pos[d], 1);
        csr[p] = ei[e];
    }
}

// BN scale/shift: sc = g/sqrt(var+eps), sh = be - mu*sc
__global__ void k_bnpar(const float* __restrict__ stats, const float* __restrict__ g,
                        const float* __restrict__ be, float* __restrict__ par) {
    int c = threadIdx.x;  // 128
    const float inv = 1.0f / (float)NN;
    float mu = stats[c] * inv;
    float var = stats[128 + c] * inv - mu * mu;
    float sc = g[c] / sqrtf(var + BN_EPS);
    par[c] = sc;
    par[128 + c] = be[c] - mu * sc;
}

// layer-0 gather: fp32 x -> bf16 agg.  16 lanes/node, 8 floats/lane.
__global__ void k_gather0(const float* __restrict__ x, const int* __restrict__ offs,
                          const int* __restrict__ csr, short* __restrict__ agg) {
    int tt = blockIdx.x * 256 + threadIdx.x;
    int n = tt >> 4, l = tt & 15;
    if (n >= NN) return;
    int j0 = offs[n], j1 = offs[n + 1];
    const float4* xr = (const float4*)(x + (size_t)n * 128) + l * 2;
    float4 a0 = xr[0], a1 = xr[1];
    float f[8] = {a0.x, a0.y, a0.z, a0.w, a1.x, a1.y, a1.z, a1.w};
    for (int j = j0; j < j1; ++j) {
        int s = csr[j];
        const float4* sr = (const float4*)(x + (size_t)s * 128) + l * 2;
        float4 b0 = sr[0], b1 = sr[1];
        f[0] += b0.x; f[1] += b0.y; f[2] += b0.z; f[3] += b0.w;
        f[4] += b1.x; f[5] += b1.y; f[6] += b1.z; f[7] += b1.w;
    }
    short8 o;
#pragma unroll
    for (int j = 0; j < 8; ++j) o[j] = f2bf(f[j]);
    *(short8*)(agg + (size_t)n * 128 + l * 8) = o;
}

// bf16 gather with fused BN+ReLU on every gathered row
__global__ void k_gatherb(const short* __restrict__ h, const int* __restrict__ offs,
                          const int* __restrict__ csr, const float* __restrict__ par,
                          short* __restrict__ agg) {
    int tt = blockIdx.x * 256 + threadIdx.x;
    int n = tt >> 4, l = tt & 15;
    if (n >= NN) return;
    float sc[8], sh[8];
    {
        const float4* p = (const float4*)par + l * 2;
        float4 s0 = p[0], s1 = p[1];
        const float4* q = (const float4*)(par + 128) + l * 2;
        float4 h0 = q[0], h1 = q[1];
        sc[0] = s0.x; sc[1] = s0.y; sc[2] = s0.z; sc[3] = s0.w;
        sc[4] = s1.x; sc[5] = s1.y; sc[6] = s1.z; sc[7] = s1.w;
        sh[0] = h0.x; sh[1] = h0.y; sh[2] = h0.z; sh[3] = h0.w;
        sh[4] = h1.x; sh[5] = h1.y; sh[6] = h1.z; sh[7] = h1.w;
    }
    int j0 = offs[n], j1 = offs[n + 1];
    short8 v = *(const short8*)(h + (size_t)n * 128 + l * 8);
    float f[8];
#pragma unroll
    for (int j = 0; j < 8; ++j) f[j] = fmaxf(fmaf(bf2f(v[j]), sc[j], sh[j]), 0.f);
    for (int j = j0; j < j1; ++j) {
        int s = csr[j];
        short8 w = *(const short8*)(h + (size_t)s * 128 + l * 8);
#pragma unroll
        for (int k = 0; k < 8; ++k) f[k] += fmaxf(fmaf(bf2f(w[k]), sc[k], sh[k]), 0.f);
    }
    short8 o;
#pragma unroll
    for (int j = 0; j < 8; ++j) o[j] = f2bf(f[j]);
    *(short8*)(agg + (size_t)n * 128 + l * 8) = o;
}

// ---------------- fused GIN MLP, bf16 MFMA ----------------
// 64-row tile. 4 waves; wave w: all 64 rows x cols [w*32, w*32+32).
// A layout (16x16x32): lane reads A[m=lane&15][k=(lane>>4)*8 + j]
// B layout:            lane reads B[n=lane&15][k=(lane>>4)*8 + j]  (Wt[n][k])
// C/D:                 col=lane&15, row=(lane>>4)*4+reg
template <bool SECOND>
__global__ __launch_bounds__(256, 3) void k_mlp(const short* __restrict__ hin,
                                                short* __restrict__ hout,
                                                const short* __restrict__ Wta,
                                                const float* __restrict__ ba,
                                                const short* __restrict__ Wtb,
                                                const float* __restrict__ bb,
                                                float* __restrict__ stats) {
    __shared__ short Asb[64][136];
    __shared__ short Wsb[128][136];
    const int t = threadIdx.x;
    const int row0 = blockIdx.x * 64;
    const int lane = t & 63, wave = t >> 6;
    const int r16 = lane & 15, q = lane >> 4;
    const int q8 = q * 8;
    const int w32 = wave * 32;

    // stage A tile (bf16 rows of hin), coalesced 16B chunks
#pragma unroll
    for (int i = 0; i < 4; ++i) {
        int f = i * 256 + t;
        int r = f >> 4, c0 = (f & 15) * 8;
        int gr = row0 + r;
        short8 v = {0, 0, 0, 0, 0, 0, 0, 0};
        if (gr < NN) v = *(const short8*)(hin + (size_t)gr * 128 + c0);
        *(short8*)&Asb[r][c0] = v;
    }
    // stage Wa^T
#pragma unroll
    for (int i = 0; i < 8; ++i) {
        int f = i * 256 + t;
        int r = f >> 4, c0 = (f & 15) * 8;
        *(short8*)&Wsb[r][c0] = *(const short8*)(Wta + r * 128 + c0);
    }
    __syncthreads();

    f32x4 acc[4][2];
#pragma unroll
    for (int rt = 0; rt < 4; ++rt)
#pragma unroll
        for (int ct = 0; ct < 2; ++ct) acc[rt][ct] = (f32x4)0.f;

#pragma unroll
    for (int kk = 0; kk < 4; ++kk) {
        short8 b0 = *(const short8*)&Wsb[w32 + r16][kk * 32 + q8];
        short8 b1 = *(const short8*)&Wsb[w32 + 16 + r16][kk * 32 + q8];
#pragma unroll
        for (int rt = 0; rt < 4; ++rt) {
            short8 a = *(const short8*)&Asb[rt * 16 + r16][kk * 32 + q8];
            acc[rt][0] = __builtin_amdgcn_mfma_f32_16x16x32_bf16(a, b0, acc[rt][0], 0, 0, 0);
            acc[rt][1] = __builtin_amdgcn_mfma_f32_16x16x32_bf16(a, b1, acc[rt][1], 0, 0, 0);
        }
    }
    __syncthreads();  // all gemm1 LDS reads done before overwriting Asb/Wsb

    // mid = relu(acc + ba) -> Asb as bf16 (C/D layout -> row-major)
    float ba0 = ba[w32 + r16], ba1 = ba[w32 + 16 + r16];
#pragma unroll
    for (int rt = 0; rt < 4; ++rt)
#pragma unroll
        for (int ct = 0; ct < 2; ++ct) {
            float bav = ct ? ba1 : ba0;
#pragma unroll
            for (int r = 0; r < 4; ++r) {
                float m = fmaxf(acc[rt][ct][r] + bav, 0.f);
                Asb[rt * 16 + q * 4 + r][w32 + ct * 16 + r16] = f2bf(m);
            }
        }

    if constexpr (!SECOND) {
        __syncthreads();
#pragma unroll
        for (int i = 0; i < 4; ++i) {
            int f = i * 256 + t;
            int r = f >> 4, c0 = (f & 15) * 8;
            int gr = row0 + r;
            if (gr < NN)
                *(short8*)(hout + (size_t)gr * 128 + c0) = *(const short8*)&Asb[r][c0];
        }
        return;
    } else {
        // stage Wb^T (Wsb reads finished at barrier above)
#pragma unroll
        for (int i = 0; i < 8; ++i) {
            int f = i * 256 + t;
            int r = f >> 4, c0 = (f & 15) * 8;
            *(short8*)&Wsb[r][c0] = *(const short8*)(Wtb + r * 128 + c0);
        }
        __syncthreads();

#pragma unroll
        for (int rt = 0; rt < 4; ++rt)
#pragma unroll
            for (int ct = 0; ct < 2; ++ct) acc[rt][ct] = (f32x4)0.f;

#pragma unroll
        for (int kk = 0; kk < 4; ++kk) {
            short8 b0 = *(const short8*)&Wsb[w32 + r16][kk * 32 + q8];
            short8 b1 = *(const short8*)&Wsb[w32 + 16 + r16][kk * 32 + q8];
#pragma unroll
            for (int rt = 0; rt < 4; ++rt) {
                short8 a = *(const short8*)&Asb[rt * 16 + r16][kk * 32 + q8];
                acc[rt][0] = __builtin_amdgcn_mfma_f32_16x16x32_bf16(a, b0, acc[rt][0], 0, 0, 0);
                acc[rt][1] = __builtin_amdgcn_mfma_f32_16x16x32_bf16(a, b1, acc[rt][1], 0, 0, 0);
            }
        }
        __syncthreads();  // all gemm2 LDS reads done

        float bb0 = bb[w32 + r16], bb1 = bb[w32 + 16 + r16];
        float s[2] = {0.f, 0.f}, ss[2] = {0.f, 0.f};
#pragma unroll
        for (int rt = 0; rt < 4; ++rt)
#pragma unroll
            for (int ct = 0; ct < 2; ++ct) {
                float bbv = ct ? bb1 : bb0;
#pragma unroll
                for (int r = 0; r < 4; ++r) {
                    int gr = row0 + rt * 16 + q * 4 + r;
                    float hv = acc[rt][ct][r] + bbv;
                    if (gr < NN) { s[ct] += hv; ss[ct] += hv * hv; }
                    Asb[rt * 16 + q * 4 + r][w32 + ct * 16 + r16] = f2bf(hv);
                }
            }
        // butterfly over the 4 row-subgroups (lanes with same lane&15)
#pragma unroll
        for (int ct = 0; ct < 2; ++ct) {
            s[ct] += __shfl_xor(s[ct], 16);
            s[ct] += __shfl_xor(s[ct], 32);
            ss[ct] += __shfl_xor(ss[ct], 16);
            ss[ct] += __shfl_xor(ss[ct], 32);
        }
        float* red = (float*)&Wsb[0][0];  // 256 floats (Wsb dead)
        if (lane < 16) {
            red[w32 + r16] = s[0];
            red[w32 + 16 + r16] = s[1];
            red[128 + w32 + r16] = ss[0];
            red[128 + w32 + 16 + r16] = ss[1];
        }
        __syncthreads();
        unsafeAtomicAdd(&stats[t & 255], red[t & 255]);
        // coalesced bf16 store of h tile
#pragma unroll
        for (int i = 0; i < 4; ++i) {
            int f = i * 256 + t;
            int r = f >> 4, c0 = (f & 15) * 8;
            int gr = row0 + r;
            if (gr < NN)
                *(short8*)(hout + (size_t)gr * 128 + c0) = *(const short8*)&Asb[r][c0];
        }
    }
}

// layer-2 second linear: z[n] = mid[n].w + b (+ BN(1) stats). 16 lanes/node.
__global__ void k_dot(const short* __restrict__ mid, const float* __restrict__ w,
                      const float* __restrict__ b2, float* __restrict__ z,
                      float* __restrict__ s2) {
    __shared__ float rs[4], rss[4];
    int t = threadIdx.x;
    int tt = blockIdx.x * 256 + t;
    int n = tt >> 4, l = tt & 15;
    float p = 0.f;
    bool valid = n < NN;
    if (valid) {
        short8 v = *(const short8*)(mid + (size_t)n * 128 + l * 8);
        const float4* wp = (const float4*)w + l * 2;
        float4 w0 = wp[0], w1 = wp[1];
        p = bf2f(v[0]) * w0.x + bf2f(v[1]) * w0.y + bf2f(v[2]) * w0.z + bf2f(v[3]) * w0.w +
            bf2f(v[4]) * w1.x + bf2f(v[5]) * w1.y + bf2f(v[6]) * w1.z + bf2f(v[7]) * w1.w;
    }
#pragma unroll
    for (int off = 1; off < 16; off <<= 1) p += __shfl_xor(p, off, 16);
    float h2 = p + b2[0];
    float sv = 0.f, ssv = 0.f;
    if (valid && l == 0) {
        z[n] = h2;
        sv = h2;
        ssv = h2 * h2;
    }
    sv += __shfl_xor(sv, 16); sv += __shfl_xor(sv, 32);
    ssv += __shfl_xor(ssv, 16); ssv += __shfl_xor(ssv, 32);
    int wv = t >> 6;
    if ((t & 63) == 0) { rs[wv] = sv; rss[wv] = ssv; }
    __syncthreads();
    if (t == 0) {
        unsafeAtomicAdd(&s2[0], rs[0] + rs[1] + rs[2] + rs[3]);
        unsafeAtomicAdd(&s2[1], rss[0] + rss[1] + rss[2] + rss[3]);
    }
}

__global__ void k_bnz_max(const float* __restrict__ zr, const float* __restrict__ s2,
                          const float* __restrict__ g2, const float* __restrict__ be2,
                          const int* __restrict__ batch, float* __restrict__ out,
                          unsigned* __restrict__ mbuf) {
    int n = blockIdx.x * 256 + threadIdx.x;
    int nn = n < NN ? n : (NN - 1);
    float mu = s2[0] / (float)NN;
    float var = s2[1] / (float)NN - mu * mu;
    float sc = g2[0] / sqrtf(var + BN_EPS);
    float z = ((zr[nn] - mu) * sc + be2[0]) / 5.0f;
    int b = batch[nn];
    if (n < NN) out[n] = z;
    float zv = (n < NN) ? z : -INFINITY;
    int b0 = __shfl(b, 0, 64), b1 = __shfl(b, 63, 64);
    if (b0 == b1) {
#pragma unroll
        for (int off = 32; off > 0; off >>= 1) zv = fmaxf(zv, __shfl_xor(zv, off, 64));
        if ((threadIdx.x & 63) == 0) atomicMax(&mbuf[b0], enc_f(zv));
    } else if (n < NN) {
        atomicMax(&mbuf[b], enc_f(z));
    }
}

__global__ void k_expsum(float* __restrict__ out, const unsigned* __restrict__ mbuf,
                         const int* __restrict__ batch, float* __restrict__ sbuf) {
    int n = blockIdx.x * 256 + threadIdx.x;
    int nn = n < NN ? n : (NN - 1);
    int b = batch[nn];
    float z = out[nn];
    float e = expf(z - dec_f(mbuf[b]));
    if (n < NN) out[n] = e;
    float sv = (n < NN) ? e : 0.f;
    int b0 = __shfl(b, 0, 64), b1 = __shfl(b, 63, 64);
    if (b0 == b1) {
#pragma unroll
        for (int off = 32; off > 0; off >>= 1) sv += __shfl_xor(sv, off, 64);
        if ((threadIdx.x & 63) == 0) unsafeAtomicAdd(&sbuf[b0], sv);
    } else if (n < NN) {
        unsafeAtomicAdd(&sbuf[b], sv);
    }
}

__global__ void k_final(float* __restrict__ out, const float* __restrict__ sbuf,
                        const int* __restrict__ batch) {
    int n = blockIdx.x * 256 + threadIdx.x;
    if (n < NN) out[n] = out[n] / (sbuf[batch[n]] + 1e-16f);
}

extern "C" void kernel_launch(void* const* d_in, const int* in_sizes, int n_in,
                              void* d_out, int out_size, void* d_ws, size_t ws_size,
                              hipStream_t stream) {
    const float* x   = (const float*)d_in[0];
    const int* ei    = (const int*)d_in[1];
    const int* batch = (const int*)d_in[2];
    const float *W0a = (const float*)d_in[3],  *b0a = (const float*)d_in[4];
    const float *W0b = (const float*)d_in[5],  *b0b = (const float*)d_in[6];
    const float *g0  = (const float*)d_in[7],  *be0 = (const float*)d_in[8];
    const float *W1a = (const float*)d_in[9],  *b1a = (const float*)d_in[10];
    const float *W1b = (const float*)d_in[11], *b1b = (const float*)d_in[12];
    const float *g1  = (const float*)d_in[13], *be1 = (const float*)d_in[14];
    const float *W2a = (const float*)d_in[15], *b2a = (const float*)d_in[16];
    const float *W2b = (const float*)d_in[17], *b2b = (const float*)d_in[18];
    const float *g2  = (const float*)d_in[19], *be2 = (const float*)d_in[20];
    float* out = (float*)d_out;

    char* wsb = (char*)d_ws;
    short* Abf = (short*)wsb;
    short* Bbf = (short*)(wsb + 25600000);
    float* Zb  = (float*)(wsb + 51200000);
    float* SM  = (float*)(wsb + 51600000);
    float* S0 = SM;
    float* S1 = SM + 256;
    float* S2 = SM + 512;
    unsigned* MB = (unsigned*)(SM + 514);
    float* SB = SM + 642;
    float* P0 = SM + 896;
    float* P1 = SM + 1152;
    int* offs  = (int*)(wsb + 51606144);
    int* bsums = (int*)(wsb + 52006148);
    int* csr   = (int*)(wsb + 52006660);
    short* Wt  = (short*)(wsb + 54566672);
    // deg/pos alias Abf during CSR build
    int* deg = (int*)wsb;
    int* pos = (int*)(wsb + 400000);

    const int gE   = (EE + 255) / 256;   // 2500
    const int gN   = (NN + 255) / 256;   // 391
    const int gG16 = (NN * 16) / 256;    // 6250
    const int gMlp = (NN + 63) / 64;     // 1563

    k_init_small<<<1, 1024, 0, stream>>>(SM);
    k_prepw<<<320, 256, 0, stream>>>(W0a, W0b, W1a, W1b, W2a, Wt);

    // ---- CSR build (reused all 3 layers) ----
    k_zero_i<<<gN, 256, 0, stream>>>(deg, NN);
    k_hist<<<gE, 256, 0, stream>>>(ei, deg);
    k_scan1<<<NBLK, 1024, 0, stream>>>(deg, offs, bsums);
    k_scan2<<<1, 128, 0, stream>>>(bsums);
    k_scan3<<<NBLK, 1024, 0, stream>>>(offs, bsums, pos);
    k_fill<<<gE, 256, 0, stream>>>(ei, pos, csr);

    // layer 0
    k_gather0<<<gG16, 256, 0, stream>>>(x, offs, csr, Abf);
    k_mlp<true><<<gMlp, 256, 0, stream>>>(Abf, Abf, Wt, b0a, Wt + 16384, b0b, S0);
    k_bnpar<<<1, 128, 0, stream>>>(S0, g0, be0, P0);
    // layer 1 (BN0+ReLU fused into gather)
    k_gatherb<<<gG16, 256, 0, stream>>>(Abf, offs, csr, P0, Bbf);
    k_mlp<true><<<gMlp, 256, 0, stream>>>(Bbf, Bbf, Wt + 2 * 16384, b1a, Wt + 3 * 16384, b1b, S1);
    k_bnpar<<<1, 128, 0, stream>>>(S1, g1, be1, P1);
    // layer 2 (BN1+ReLU fused into gather)
    k_gatherb<<<gG16, 256, 0, stream>>>(Bbf, offs, csr, P1, Abf);
    k_mlp<false><<<gMlp, 256, 0, stream>>>(Abf, Abf, Wt + 4 * 16384, b2a, nullptr, nullptr, nullptr);
    k_dot<<<gG16, 256, 0, stream>>>(Abf, W2b, b2b, Zb, S2);

    // BN(1) + segment softmax (temperature 5)
    k_bnz_max<<<gN, 256, 0, stream>>>(Zb, S2, g2, be2, batch, out, MB);
    k_expsum<<<gN, 256, 0, stream>>>(out, MB, batch, SB);
    k_final<<<gN, 256, 0, stream>>>(out, SB, batch);
}

// Round 5
// 464.166 us; speedup vs baseline: 8.3904x; 1.4005x over previous
//
#include <hip/hip_runtime.h>
#include <math.h>

#define NN 100000
#define EE 640000
#define GG 128
#define BN_EPS 1e-5f
#define NBLK 98  // ceil(NN/1024)

typedef __attribute__((ext_vector_type(8))) short short8;
typedef __attribute__((ext_vector_type(4))) float f32x4;

// ---------------- ws layout (byte offsets) ----------------
// Abf : [0,          25,600,000)   N x 128 bf16
// Bbf : [25,600,000, 51,200,000)   N x 128 bf16
// Z   : [51,200,000, 51,600,000)   N fp32
// SM  : [51,600,000, +19,520)      S0r(8x256) S1r(8x256) S2r(8x2) MB(128) SB(128) P0(256) P1(256)
// offs: [51,620,000, +400,004)     N+1 int
// bsum: [52,020,004, +512)
// csr : [52,020,516, +2,560,000)
// Wt  : [54,580,544, +163,840)     5 x 128x128 bf16 (transposed weights), 16B aligned
// deg/pos alias Abf region during CSR build (Abf not yet live).

__device__ __forceinline__ unsigned enc_f(float f) {
    unsigned u = __float_as_uint(f);
    return (u & 0x80000000u) ? ~u : (u | 0x80000000u);
}
__device__ __forceinline__ float dec_f(unsigned k) {
    unsigned u = (k & 0x80000000u) ? (k ^ 0x80000000u) : ~k;
    return __uint_as_float(u);
}
__device__ __forceinline__ short f2bf(float f) {
    unsigned u = __float_as_uint(f);
    u += 0x7fffu + ((u >> 16) & 1);
    return (short)(u >> 16);
}
__device__ __forceinline__ float bf2f(short s) {
    return __uint_as_float(((unsigned)(unsigned short)s) << 16);
}

__global__ void k_init_small(float* sm, int n) {
    int i = blockIdx.x * 256 + threadIdx.x;
    if (i < n) sm[i] = 0.0f;
}

__global__ void k_zero_i(int* p, int n) {
    int i = blockIdx.x * 256 + threadIdx.x;
    if (i < n) p[i] = 0;
}

// W (fp32 [k][n]) -> Wt (bf16 [n][k]) for 5 weights
__global__ void k_prepw(const float* __restrict__ W0a, const float* __restrict__ W0b,
                        const float* __restrict__ W1a, const float* __restrict__ W1b,
                        const float* __restrict__ W2a, short* __restrict__ Wt) {
    int idx = blockIdx.x * 256 + threadIdx.x;  // 5*16384
    int wi = idx >> 14, r = idx & 16383;
    const float* W = (wi == 0) ? W0a : (wi == 1) ? W0b : (wi == 2) ? W1a
                    : (wi == 3) ? W1b : W2a;
    int k = r >> 7, n = r & 127;
    Wt[wi * 16384 + n * 128 + k] = f2bf(W[k * 128 + n]);
}

// ---------------- CSR build ----------------
__global__ void k_hist(const int* __restrict__ ei, int* __restrict__ deg) {
    int e = blockIdx.x * 256 + threadIdx.x;
    if (e < EE) atomicAdd(&deg[ei[EE + e]], 1);
}

__global__ __launch_bounds__(1024) void k_scan1(const int* __restrict__ deg,
                                                int* __restrict__ offs,
                                                int* __restrict__ bsums) {
    __shared__ int sm[1024];
    int t = threadIdx.x;
    int i = blockIdx.x * 1024 + t;
    int v = (i < NN) ? deg[i] : 0;
    sm[t] = v;
    __syncthreads();
    for (int off = 1; off < 1024; off <<= 1) {
        int add = (t >= off) ? sm[t - off] : 0;
        __syncthreads();
        sm[t] += add;
        __syncthreads();
    }
    if (i < NN) offs[i] = sm[t] - v;
    if (t == 1023) bsums[blockIdx.x] = sm[1023];
}

__global__ void k_scan2(int* bsums) {
    __shared__ int sm[128];
    int t = threadIdx.x;
    int v = (t < NBLK) ? bsums[t] : 0;
    sm[t] = v;
    __syncthreads();
    for (int off = 1; off < 128; off <<= 1) {
        int add = (t >= off) ? sm[t - off] : 0;
        __syncthreads();
        sm[t] += add;
        __syncthreads();
    }
    if (t < NBLK) bsums[t] = sm[t] - v;
}

__global__ __launch_bounds__(1024) void k_scan3(int* __restrict__ offs,
                                                const int* __restrict__ bsums,
                                                int* __restrict__ pos) {
    int t = threadIdx.x;
    int i = blockIdx.x * 1024 + t;
    if (i < NN) {
        int o = offs[i] + bsums[blockIdx.x];
        offs[i] = o;
        pos[i] = o;
    }
    if (i == 0) offs[NN] = EE;
}

__global__ void k_fill(const int* __restrict__ ei, int* __restrict__ pos,
                       int* __restrict__ csr) {
    int e = blockIdx.x * 256 + threadIdx.x;
    if (e < EE) {
        int d = ei[EE + e];
        int p = atomicAdd(&pos[d], 1);
        csr[p] = ei[e];
    }
}

// BN scale/shift from 8-replica stats: sc = g/sqrt(var+eps), sh = be - mu*sc
__global__ void k_bnpar(const float* __restrict__ rep, const float* __restrict__ g,
                        const float* __restrict__ be, float* __restrict__ par) {
    int c = threadIdx.x;  // 128
    float s = 0.f, ss = 0.f;
#pragma unroll
    for (int r = 0; r < 8; ++r) {
        s += rep[r * 256 + c];
        ss += rep[r * 256 + 128 + c];
    }
    const float inv = 1.0f / (float)NN;
    float mu = s * inv;
    float var = ss * inv - mu * mu;
    float sc = g[c] / sqrtf(var + BN_EPS);
    par[c] = sc;
    par[128 + c] = be[c] - mu * sc;
}

// layer-0 gather: fp32 x -> bf16 agg.  16 lanes/node, 8 floats/lane.
__global__ void k_gather0(const float* __restrict__ x, const int* __restrict__ offs,
                          const int* __restrict__ csr, short* __restrict__ agg) {
    int tt = blockIdx.x * 256 + threadIdx.x;
    int n = tt >> 4, l = tt & 15;
    if (n >= NN) return;
    int j0 = offs[n], j1 = offs[n + 1];
    const float4* xr = (const float4*)(x + (size_t)n * 128) + l * 2;
    float4 a0 = xr[0], a1 = xr[1];
    float f[8] = {a0.x, a0.y, a0.z, a0.w, a1.x, a1.y, a1.z, a1.w};
    for (int j = j0; j < j1; ++j) {
        int s = csr[j];
        const float4* sr = (const float4*)(x + (size_t)s * 128) + l * 2;
        float4 b0 = sr[0], b1 = sr[1];
        f[0] += b0.x; f[1] += b0.y; f[2] += b0.z; f[3] += b0.w;
        f[4] += b1.x; f[5] += b1.y; f[6] += b1.z; f[7] += b1.w;
    }
    short8 o;
#pragma unroll
    for (int j = 0; j < 8; ++j) o[j] = f2bf(f[j]);
    *(short8*)(agg + (size_t)n * 128 + l * 8) = o;
}

// bf16 gather with fused BN+ReLU on every gathered row
__global__ void k_gatherb(const short* __restrict__ h, const int* __restrict__ offs,
                          const int* __restrict__ csr, const float* __restrict__ par,
                          short* __restrict__ agg) {
    int tt = blockIdx.x * 256 + threadIdx.x;
    int n = tt >> 4, l = tt & 15;
    if (n >= NN) return;
    float sc[8], sh[8];
    {
        const float4* p = (const float4*)par + l * 2;
        float4 s0 = p[0], s1 = p[1];
        const float4* q = (const float4*)(par + 128) + l * 2;
        float4 h0 = q[0], h1 = q[1];
        sc[0] = s0.x; sc[1] = s0.y; sc[2] = s0.z; sc[3] = s0.w;
        sc[4] = s1.x; sc[5] = s1.y; sc[6] = s1.z; sc[7] = s1.w;
        sh[0] = h0.x; sh[1] = h0.y; sh[2] = h0.z; sh[3] = h0.w;
        sh[4] = h1.x; sh[5] = h1.y; sh[6] = h1.z; sh[7] = h1.w;
    }
    int j0 = offs[n], j1 = offs[n + 1];
    short8 v = *(const short8*)(h + (size_t)n * 128 + l * 8);
    float f[8];
#pragma unroll
    for (int j = 0; j < 8; ++j) f[j] = fmaxf(fmaf(bf2f(v[j]), sc[j], sh[j]), 0.f);
    for (int j = j0; j < j1; ++j) {
        int s = csr[j];
        short8 w = *(const short8*)(h + (size_t)s * 128 + l * 8);
#pragma unroll
        for (int k = 0; k < 8; ++k) f[k] += fmaxf(fmaf(bf2f(w[k]), sc[k], sh[k]), 0.f);
    }
    short8 o;
#pragma unroll
    for (int j = 0; j < 8; ++j) o[j] = f2bf(f[j]);
    *(short8*)(agg + (size_t)n * 128 + l * 8) = o;
}

// ---------------- fused GIN MLP, bf16 MFMA ----------------
// 64-row tile. 4 waves; wave w: all 64 rows x cols [w*32, w*32+32).
// SECOND=true : gemm1(+bias,ReLU) -> gemm2(+bias) -> hout + BN stats (8-replica atomics)
// SECOND=false: gemm1(+bias,ReLU) -> fused dot with w2 (+b2) -> z + (s,ss) replicas
template <bool SECOND>
__global__ __launch_bounds__(256, 3) void k_mlp(const short* __restrict__ hin,
                                                const short* __restrict__ Wta,
                                                const float* __restrict__ ba,
                                                const short* __restrict__ Wtb,
                                                const float* __restrict__ bb,
                                                short* __restrict__ hout,
                                                float* __restrict__ statsRep,
                                                const float* __restrict__ w2,
                                                const float* __restrict__ b2,
                                                float* __restrict__ z,
                                                float* __restrict__ s2rep) {
    __shared__ short Asb[64][136];
    __shared__ short Wsb[128][136];
    __shared__ float rsm[8];
    const int t = threadIdx.x;
    const int row0 = blockIdx.x * 64;
    const int lane = t & 63, wave = t >> 6;
    const int r16 = lane & 15, q = lane >> 4;
    const int q8 = q * 8;
    const int w32 = wave * 32;

    // stage A tile (bf16 rows of hin), coalesced 16B chunks
#pragma unroll
    for (int i = 0; i < 4; ++i) {
        int f = i * 256 + t;
        int r = f >> 4, c0 = (f & 15) * 8;
        int gr = row0 + r;
        short8 v = {0, 0, 0, 0, 0, 0, 0, 0};
        if (gr < NN) v = *(const short8*)(hin + (size_t)gr * 128 + c0);
        *(short8*)&Asb[r][c0] = v;
    }
    // stage Wa^T
#pragma unroll
    for (int i = 0; i < 8; ++i) {
        int f = i * 256 + t;
        int r = f >> 4, c0 = (f & 15) * 8;
        *(short8*)&Wsb[r][c0] = *(const short8*)(Wta + r * 128 + c0);
    }
    __syncthreads();

    f32x4 acc[4][2];
#pragma unroll
    for (int rt = 0; rt < 4; ++rt)
#pragma unroll
        for (int ct = 0; ct < 2; ++ct) acc[rt][ct] = (f32x4)0.f;

#pragma unroll
    for (int kk = 0; kk < 4; ++kk) {
        short8 b0 = *(const short8*)&Wsb[w32 + r16][kk * 32 + q8];
        short8 b1 = *(const short8*)&Wsb[w32 + 16 + r16][kk * 32 + q8];
#pragma unroll
        for (int rt = 0; rt < 4; ++rt) {
            short8 a = *(const short8*)&Asb[rt * 16 + r16][kk * 32 + q8];
            acc[rt][0] = __builtin_amdgcn_mfma_f32_16x16x32_bf16(a, b0, acc[rt][0], 0, 0, 0);
            acc[rt][1] = __builtin_amdgcn_mfma_f32_16x16x32_bf16(a, b1, acc[rt][1], 0, 0, 0);
        }
    }
    __syncthreads();  // all gemm1 LDS reads done before overwriting Asb/Wsb

    // mid = relu(acc + ba) -> Asb as bf16 (C/D layout -> row-major)
    float ba0 = ba[w32 + r16], ba1 = ba[w32 + 16 + r16];
#pragma unroll
    for (int rt = 0; rt < 4; ++rt)
#pragma unroll
        for (int ct = 0; ct < 2; ++ct) {
            float bav = ct ? ba1 : ba0;
#pragma unroll
            for (int r = 0; r < 4; ++r) {
                float m = fmaxf(acc[rt][ct][r] + bav, 0.f);
                Asb[rt * 16 + q * 4 + r][w32 + ct * 16 + r16] = f2bf(m);
            }
        }

    if constexpr (!SECOND) {
        __syncthreads();  // mid fully in Asb
        // fused final linear: z[row] = mid[row] . w2 + b2, plus (s,ss) stats
        const int l16 = t & 15, rr = t >> 4;
        float4 w0 = ((const float4*)w2)[l16 * 2];
        float4 w1 = ((const float4*)w2)[l16 * 2 + 1];
        float b2v = b2[0];
        float s = 0.f, ss = 0.f;
#pragma unroll
        for (int pass = 0; pass < 4; ++pass) {
            int r = pass * 16 + rr;
            short8 v = *(const short8*)&Asb[r][l16 * 8];
            float p = bf2f(v[0]) * w0.x + bf2f(v[1]) * w0.y + bf2f(v[2]) * w0.z +
                      bf2f(v[3]) * w0.w + bf2f(v[4]) * w1.x + bf2f(v[5]) * w1.y +
                      bf2f(v[6]) * w1.z + bf2f(v[7]) * w1.w;
#pragma unroll
            for (int off = 1; off < 16; off <<= 1) p += __shfl_xor(p, off, 16);
            int gr = row0 + r;
            if (l16 == 0 && gr < NN) {
                float h2 = p + b2v;
                z[gr] = h2;
                s += h2;
                ss += h2 * h2;
            }
        }
        s += __shfl_xor(s, 16); s += __shfl_xor(s, 32);
        ss += __shfl_xor(ss, 16); ss += __shfl_xor(ss, 32);
        if ((t & 63) == 0) { rsm[wave * 2] = s; rsm[wave * 2 + 1] = ss; }
        __syncthreads();
        if (t == 0) {
            float S = rsm[0] + rsm[2] + rsm[4] + rsm[6];
            float SS = rsm[1] + rsm[3] + rsm[5] + rsm[7];
            int rep = (blockIdx.x & 7) * 2;
            unsafeAtomicAdd(&s2rep[rep], S);
            unsafeAtomicAdd(&s2rep[rep + 1], SS);
        }
        return;
    } else {
        // stage Wb^T (Wsb reads finished at barrier above)
#pragma unroll
        for (int i = 0; i < 8; ++i) {
            int f = i * 256 + t;
            int r = f >> 4, c0 = (f & 15) * 8;
            *(short8*)&Wsb[r][c0] = *(const short8*)(Wtb + r * 128 + c0);
        }
        __syncthreads();

#pragma unroll
        for (int rt = 0; rt < 4; ++rt)
#pragma unroll
            for (int ct = 0; ct < 2; ++ct) acc[rt][ct] = (f32x4)0.f;

#pragma unroll
        for (int kk = 0; kk < 4; ++kk) {
            short8 b0 = *(const short8*)&Wsb[w32 + r16][kk * 32 + q8];
            short8 b1 = *(const short8*)&Wsb[w32 + 16 + r16][kk * 32 + q8];
#pragma unroll
            for (int rt = 0; rt < 4; ++rt) {
                short8 a = *(const short8*)&Asb[rt * 16 + r16][kk * 32 + q8];
                acc[rt][0] = __builtin_amdgcn_mfma_f32_16x16x32_bf16(a, b0, acc[rt][0], 0, 0, 0);
                acc[rt][1] = __builtin_amdgcn_mfma_f32_16x16x32_bf16(a, b1, acc[rt][1], 0, 0, 0);
            }
        }
        __syncthreads();  // all gemm2 LDS reads done

        float bb0 = bb[w32 + r16], bb1 = bb[w32 + 16 + r16];
        float s[2] = {0.f, 0.f}, ss[2] = {0.f, 0.f};
#pragma unroll
        for (int rt = 0; rt < 4; ++rt)
#pragma unroll
            for (int ct = 0; ct < 2; ++ct) {
                float bbv = ct ? bb1 : bb0;
#pragma unroll
                for (int r = 0; r < 4; ++r) {
                    int gr = row0 + rt * 16 + q * 4 + r;
                    float hv = acc[rt][ct][r] + bbv;
                    if (gr < NN) { s[ct] += hv; ss[ct] += hv * hv; }
                    Asb[rt * 16 + q * 4 + r][w32 + ct * 16 + r16] = f2bf(hv);
                }
            }
        // butterfly over the 4 row-subgroups (lanes with same lane&15)
#pragma unroll
        for (int ct = 0; ct < 2; ++ct) {
            s[ct] += __shfl_xor(s[ct], 16);
            s[ct] += __shfl_xor(s[ct], 32);
            ss[ct] += __shfl_xor(ss[ct], 16);
            ss[ct] += __shfl_xor(ss[ct], 32);
        }
        float* red = (float*)&Wsb[0][0];  // 256 floats (Wsb dead)
        if (lane < 16) {
            red[w32 + r16] = s[0];
            red[w32 + 16 + r16] = s[1];
            red[128 + w32 + r16] = ss[0];
            red[128 + w32 + 16 + r16] = ss[1];
        }
        __syncthreads();
        unsafeAtomicAdd(&statsRep[(blockIdx.x & 7) * 256 + t], red[t]);
        // coalesced bf16 store of h tile
#pragma unroll
        for (int i = 0; i < 4; ++i) {
            int f = i * 256 + t;
            int r = f >> 4, c0 = (f & 15) * 8;
            int gr = row0 + r;
            if (gr < NN)
                *(short8*)(hout + (size_t)gr * 128 + c0) = *(const short8*)&Asb[r][c0];
        }
    }
}

__global__ void k_bnz_max(const float* __restrict__ zr, const float* __restrict__ s2rep,
                          const float* __restrict__ g2, const float* __restrict__ be2,
                          const int* __restrict__ batch, float* __restrict__ out,
                          unsigned* __restrict__ mbuf) {
    int n = blockIdx.x * 256 + threadIdx.x;
    int nn = n < NN ? n : (NN - 1);
    float s = 0.f, ssq = 0.f;
#pragma unroll
    for (int i = 0; i < 8; ++i) { s += s2rep[i * 2]; ssq += s2rep[i * 2 + 1]; }
    float mu = s / (float)NN;
    float var = ssq / (float)NN - mu * mu;
    float sc = g2[0] / sqrtf(var + BN_EPS);
    float z = ((zr[nn] - mu) * sc + be2[0]) / 5.0f;
    int b = batch[nn];
    if (n < NN) out[n] = z;
    float zv = (n < NN) ? z : -INFINITY;
    int b0 = __shfl(b, 0, 64), b1 = __shfl(b, 63, 64);
    if (b0 == b1) {
#pragma unroll
        for (int off = 32; off > 0; off >>= 1) zv = fmaxf(zv, __shfl_xor(zv, off, 64));
        if ((threadIdx.x & 63) == 0) atomicMax(&mbuf[b0], enc_f(zv));
    } else if (n < NN) {
        atomicMax(&mbuf[b], enc_f(z));
    }
}

__global__ void k_expsum(float* __restrict__ out, const unsigned* __restrict__ mbuf,
                         const int* __restrict__ batch, float* __restrict__ sbuf) {
    int n = blockIdx.x * 256 + threadIdx.x;
    int nn = n < NN ? n : (NN - 1);
    int b = batch[nn];
    float z = out[nn];
    float e = expf(z - dec_f(mbuf[b]));
    if (n < NN) out[n] = e;
    float sv = (n < NN) ? e : 0.f;
    int b0 = __shfl(b, 0, 64), b1 = __shfl(b, 63, 64);
    if (b0 == b1) {
#pragma unroll
        for (int off = 32; off > 0; off >>= 1) sv += __shfl_xor(sv, off, 64);
        if ((threadIdx.x & 63) == 0) unsafeAtomicAdd(&sbuf[b0], sv);
    } else if (n < NN) {
        unsafeAtomicAdd(&sbuf[b], sv);
    }
}

__global__ void k_final(float* __restrict__ out, const float* __restrict__ sbuf,
                        const int* __restrict__ batch) {
    int n = blockIdx.x * 256 + threadIdx.x;
    if (n < NN) out[n] = out[n] / (sbuf[batch[n]] + 1e-16f);
}

extern "C" void kernel_launch(void* const* d_in, const int* in_sizes, int n_in,
                              void* d_out, int out_size, void* d_ws, size_t ws_size,
                              hipStream_t stream) {
    const float* x   = (const float*)d_in[0];
    const int* ei    = (const int*)d_in[1];
    const int* batch = (const int*)d_in[2];
    const float *W0a = (const float*)d_in[3],  *b0a = (const float*)d_in[4];
    const float *W0b = (const float*)d_in[5],  *b0b = (const float*)d_in[6];
    const float *g0  = (const float*)d_in[7],  *be0 = (const float*)d_in[8];
    const float *W1a = (const float*)d_in[9],  *b1a = (const float*)d_in[10];
    const float *W1b = (const float*)d_in[11], *b1b = (const float*)d_in[12];
    const float *g1  = (const float*)d_in[13], *be1 = (const float*)d_in[14];
    const float *W2a = (const float*)d_in[15], *b2a = (const float*)d_in[16];
    const float *W2b = (const float*)d_in[17], *b2b = (const float*)d_in[18];
    const float *g2  = (const float*)d_in[19], *be2 = (const float*)d_in[20];
    float* out = (float*)d_out;

    char* wsb = (char*)d_ws;
    short* Abf = (short*)wsb;
    short* Bbf = (short*)(wsb + 25600000);
    float* Zb  = (float*)(wsb + 51200000);
    float* SMf = (float*)(wsb + 51600000);
    float* S0r = SMf;               // 8 x 256
    float* S1r = SMf + 2048;        // 8 x 256
    float* S2r = SMf + 4096;        // 8 x 2
    unsigned* MB = (unsigned*)(SMf + 4112);  // 128
    float* SB = SMf + 4240;         // 128
    float* P0 = SMf + 4368;         // 256
    float* P1 = SMf + 4624;         // 256
    int* offs  = (int*)(wsb + 51620000);
    int* bsums = (int*)(wsb + 52020004);
    int* csr   = (int*)(wsb + 52020516);
    short* Wt  = (short*)(wsb + 54580544);
    // deg/pos alias Abf during CSR build
    int* deg = (int*)wsb;
    int* pos = (int*)(wsb + 400000);

    const int gE   = (EE + 255) / 256;   // 2500
    const int gN   = (NN + 255) / 256;   // 391
    const int gG16 = (NN * 16) / 256;    // 6250
    const int gMlp = (NN + 63) / 64;     // 1563

    k_init_small<<<18, 256, 0, stream>>>(SMf, 4368);
    k_prepw<<<320, 256, 0, stream>>>(W0a, W0b, W1a, W1b, W2a, Wt);

    // ---- CSR build (reused all 3 layers) ----
    k_zero_i<<<gN, 256, 0, stream>>>(deg, NN);
    k_hist<<<gE, 256, 0, stream>>>(ei, deg);
    k_scan1<<<NBLK, 1024, 0, stream>>>(deg, offs, bsums);
    k_scan2<<<1, 128, 0, stream>>>(bsums);
    k_scan3<<<NBLK, 1024, 0, stream>>>(offs, bsums, pos);
    k_fill<<<gE, 256, 0, stream>>>(ei, pos, csr);

    // layer 0
    k_gather0<<<gG16, 256, 0, stream>>>(x, offs, csr, Abf);
    k_mlp<true><<<gMlp, 256, 0, stream>>>(Abf, Wt, b0a, Wt + 16384, b0b, Abf, S0r,
                                          nullptr, nullptr, nullptr, nullptr);
    k_bnpar<<<1, 128, 0, stream>>>(S0r, g0, be0, P0);
    // layer 1 (BN0+ReLU fused into gather)
    k_gatherb<<<gG16, 256, 0, stream>>>(Abf, offs, csr, P0, Bbf);
    k_mlp<true><<<gMlp, 256, 0, stream>>>(Bbf, Wt + 2 * 16384, b1a, Wt + 3 * 16384, b1b,
                                          Bbf, S1r, nullptr, nullptr, nullptr, nullptr);
    k_bnpar<<<1, 128, 0, stream>>>(S1r, g1, be1, P1);
    // layer 2 (BN1+ReLU fused into gather; final linear fused into mlp)
    k_gatherb<<<gG16, 256, 0, stream>>>(Bbf, offs, csr, P1, Abf);
    k_mlp<false><<<gMlp, 256, 0, stream>>>(Abf, Wt + 4 * 16384, b2a, nullptr, nullptr,
                                           nullptr, nullptr, W2b, b2b, Zb, S2r);

    // BN(1) + segment softmax (temperature 5)
    k_bnz_max<<<gN, 256, 0, stream>>>(Zb, S2r, g2, be2, batch, out, MB);
    k_expsum<<<gN, 256, 0, stream>>>(out, MB, batch, SB);
    k_final<<<gN, 256, 0, stream>>>(out, SB, batch);
}

// Round 6
// 401.086 us; speedup vs baseline: 9.7100x; 1.1573x over previous
//
#include <hip/hip_runtime.h>
#include <math.h>

#define NN 100000
#define EE 640000
#define GG 128
#define BN_EPS 1e-5f
#define NBLK 98  // ceil(NN/1024)

typedef __attribute__((ext_vector_type(8))) short short8;
typedef __attribute__((ext_vector_type(4))) float f32x4;

// ---------------- ws layout (byte offsets) ----------------
// Abf : [0,          25,600,000)   N x 128 bf16
// Bbf : [25,600,000, 51,200,000)   N x 128 bf16
// Z   : [51,200,000, 51,600,000)   N fp32
// SM  : [51,600,000, +16,448)      S0r(8x256) S1r(8x256) S2r(8x2)
// offs: [51,620,000, +400,004)     N+1 int
// bsum: [52,020,004, +512)
// csr : [52,020,516, +2,560,000)
// Wt  : [54,580,544, +163,840)     5 x 128x128 bf16 (transposed weights), 16B aligned
// deg/pos alias Abf region during CSR build (Abf not yet live).

__device__ __forceinline__ short f2bf(float f) {
    unsigned u = __float_as_uint(f);
    u += 0x7fffu + ((u >> 16) & 1);
    return (short)(u >> 16);
}
__device__ __forceinline__ float bf2f(short s) {
    return __uint_as_float(((unsigned)(unsigned short)s) << 16);
}
// XOR-swizzled LDS addressing (16B chunks), padding-free & ~conflict-free
__device__ __forceinline__ int swz(int row, int chunk) {
    return row * 128 + ((chunk ^ (row & 15)) << 3);
}
__device__ __forceinline__ int swze(int row, int col) {
    return row * 128 + (((col >> 3) ^ (row & 15)) << 3) + (col & 7);
}

// setup: transpose+convert 5 weights to bf16, zero deg and stats
__global__ void k_setup(const float* __restrict__ W0a, const float* __restrict__ W0b,
                        const float* __restrict__ W1a, const float* __restrict__ W1b,
                        const float* __restrict__ W2a, short* __restrict__ Wt,
                        int* __restrict__ deg, float* __restrict__ smf) {
    int idx = blockIdx.x * 256 + threadIdx.x;
    if (idx < 81920) {
        int wi = idx >> 14, r = idx & 16383;
        const float* W = (wi == 0) ? W0a : (wi == 1) ? W0b : (wi == 2) ? W1a
                        : (wi == 3) ? W1b : W2a;
        int k = r >> 7, n = r & 127;
        Wt[wi * 16384 + n * 128 + k] = f2bf(W[k * 128 + n]);
    }
    if (idx < NN) deg[idx] = 0;
    if (idx < 4112) smf[idx] = 0.0f;
}

// ---------------- CSR build ----------------
__global__ void k_hist(const int* __restrict__ ei, int* __restrict__ deg) {
    int e = blockIdx.x * 256 + threadIdx.x;
    if (e < EE) atomicAdd(&deg[ei[EE + e]], 1);
}

__global__ __launch_bounds__(1024) void k_scan1(const int* __restrict__ deg,
                                                int* __restrict__ offs,
                                                int* __restrict__ bsums) {
    __shared__ int sm[1024];
    int t = threadIdx.x;
    int i = blockIdx.x * 1024 + t;
    int v = (i < NN) ? deg[i] : 0;
    sm[t] = v;
    __syncthreads();
    for (int off = 1; off < 1024; off <<= 1) {
        int add = (t >= off) ? sm[t - off] : 0;
        __syncthreads();
        sm[t] += add;
        __syncthreads();
    }
    if (i < NN) offs[i] = sm[t] - v;
    if (t == 1023) bsums[blockIdx.x] = sm[1023];
}

__global__ void k_scan2(int* bsums) {
    __shared__ int sm[128];
    int t = threadIdx.x;
    int v = (t < NBLK) ? bsums[t] : 0;
    sm[t] = v;
    __syncthreads();
    for (int off = 1; off < 128; off <<= 1) {
        int add = (t >= off) ? sm[t - off] : 0;
        __syncthreads();
        sm[t] += add;
        __syncthreads();
    }
    if (t < NBLK) bsums[t] = sm[t] - v;
}

__global__ __launch_bounds__(1024) void k_scan3(int* __restrict__ offs,
                                                const int* __restrict__ bsums,
                                                int* __restrict__ pos) {
    int t = threadIdx.x;
    int i = blockIdx.x * 1024 + t;
    if (i < NN) {
        int o = offs[i] + bsums[blockIdx.x];
        offs[i] = o;
        pos[i] = o;
    }
    if (i == 0) offs[NN] = EE;
}

__global__ void k_fill(const int* __restrict__ ei, int* __restrict__ pos,
                       int* __restrict__ csr) {
    int e = blockIdx.x * 256 + threadIdx.x;
    if (e < EE) {
        int d = ei[EE + e];
        int p = atomicAdd(&pos[d], 1);
        csr[p] = ei[e];
    }
}

// layer-0 gather: fp32 x -> bf16 agg.  16 lanes/node, 8 floats/lane.
__global__ void k_gather0(const float* __restrict__ x, const int* __restrict__ offs,
                          const int* __restrict__ csr, short* __restrict__ agg) {
    int tt = blockIdx.x * 256 + threadIdx.x;
    int n = tt >> 4, l = tt & 15;
    if (n >= NN) return;
    int j0 = offs[n], j1 = offs[n + 1];
    const float4* xr = (const float4*)(x + (size_t)n * 128) + l * 2;
    float4 a0 = xr[0], a1 = xr[1];
    float f[8] = {a0.x, a0.y, a0.z, a0.w, a1.x, a1.y, a1.z, a1.w};
    for (int j = j0; j < j1; ++j) {
        int s = csr[j];
        const float4* sr = (const float4*)(x + (size_t)s * 128) + l * 2;
        float4 b0 = sr[0], b1 = sr[1];
        f[0] += b0.x; f[1] += b0.y; f[2] += b0.z; f[3] += b0.w;
        f[4] += b1.x; f[5] += b1.y; f[6] += b1.z; f[7] += b1.w;
    }
    short8 o;
#pragma unroll
    for (int j = 0; j < 8; ++j) o[j] = f2bf(f[j]);
    *(short8*)(agg + (size_t)n * 128 + l * 8) = o;
}

// bf16 gather with fused BN(from 8-replica stats)+ReLU on every gathered row
__global__ void k_gatherb(const short* __restrict__ h, const int* __restrict__ offs,
                          const int* __restrict__ csr, const float* __restrict__ rep,
                          const float* __restrict__ g, const float* __restrict__ be,
                          short* __restrict__ agg) {
    __shared__ float parS[128], parH[128];
    int t = threadIdx.x;
    if (t < 128) {
        float s = 0.f, ss = 0.f;
#pragma unroll
        for (int r = 0; r < 8; ++r) {
            s += rep[r * 256 + t];
            ss += rep[r * 256 + 128 + t];
        }
        const float inv = 1.0f / (float)NN;
        float mu = s * inv;
        float var = ss * inv - mu * mu;
        float sc = g[t] / sqrtf(var + BN_EPS);
        parS[t] = sc;
        parH[t] = be[t] - mu * sc;
    }
    __syncthreads();
    int tt = blockIdx.x * 256 + t;
    int n = tt >> 4, l = tt & 15;
    if (n >= NN) return;
    float sc[8], sh[8];
#pragma unroll
    for (int j = 0; j < 8; ++j) { sc[j] = parS[l * 8 + j]; sh[j] = parH[l * 8 + j]; }
    int j0 = offs[n], j1 = offs[n + 1];
    short8 v = *(const short8*)(h + (size_t)n * 128 + l * 8);
    float f[8];
#pragma unroll
    for (int j = 0; j < 8; ++j) f[j] = fmaxf(fmaf(bf2f(v[j]), sc[j], sh[j]), 0.f);
    for (int j = j0; j < j1; ++j) {
        int s = csr[j];
        short8 w = *(const short8*)(h + (size_t)s * 128 + l * 8);
#pragma unroll
        for (int k = 0; k < 8; ++k) f[k] += fmaxf(fmaf(bf2f(w[k]), sc[k], sh[k]), 0.f);
    }
    short8 o;
#pragma unroll
    for (int j = 0; j < 8; ++j) o[j] = f2bf(f[j]);
    *(short8*)(agg + (size_t)n * 128 + l * 8) = o;
}

// ---------------- fused GIN MLP, bf16 MFMA, 128x128 tile ----------------
// 4 waves; wave w = (rh = w&1, ch = w>>1): rows [rh*64,+64) x cols [ch*64,+64).
// SECOND=true : gemm1(+bias,ReLU) -> gemm2(+bias) -> hout + BN stats (8-replica)
// SECOND=false: gemm1(+bias,ReLU) -> fused dot with w2 (+b2) -> z + (s,ss) replicas
template <bool SECOND>
__global__ __launch_bounds__(256, 2) void k_mlp(const short* __restrict__ hin,
                                                const short* __restrict__ Wta,
                                                const float* __restrict__ ba,
                                                const short* __restrict__ Wtb,
                                                const float* __restrict__ bb,
                                                short* __restrict__ hout,
                                                float* __restrict__ statsRep,
                                                const float* __restrict__ w2,
                                                const float* __restrict__ b2,
                                                float* __restrict__ z,
                                                float* __restrict__ s2rep) {
    __shared__ short Asb[16384];  // 128x128 bf16, xor-swizzled chunks
    __shared__ short Wsb[16384];
    const int t = threadIdx.x;
    const int row0 = blockIdx.x * 128;
    const int lane = t & 63, wave = t >> 6;
    const int r16 = lane & 15, q = lane >> 4;
    const int rh = wave & 1, ch = wave >> 1;
    const int RA = rh * 64, CB = ch * 64;

    short8 wpre[8];
    // stage A tile + Wa^T; prefetch Wb^T into registers (overlaps gemm1)
#pragma unroll
    for (int i = 0; i < 8; ++i) {
        int f = i * 256 + t;
        int r = f >> 4, c8 = f & 15;
        int gr = row0 + r;
        short8 v = {0, 0, 0, 0, 0, 0, 0, 0};
        if (gr < NN) v = *(const short8*)(hin + (size_t)gr * 128 + c8 * 8);
        *(short8*)&Asb[swz(r, c8)] = v;
        *(short8*)&Wsb[swz(r, c8)] = *(const short8*)(Wta + r * 128 + c8 * 8);
        if constexpr (SECOND) wpre[i] = *(const short8*)(Wtb + r * 128 + c8 * 8);
    }
    __syncthreads();

    f32x4 acc[4][4];
#pragma unroll
    for (int rt = 0; rt < 4; ++rt)
#pragma unroll
        for (int ct = 0; ct < 4; ++ct) acc[rt][ct] = (f32x4)0.f;

#pragma unroll
    for (int kk = 0; kk < 4; ++kk) {
        short8 b[4], a[4];
#pragma unroll
        for (int ct = 0; ct < 4; ++ct)
            b[ct] = *(const short8*)&Wsb[swz(CB + ct * 16 + r16, kk * 4 + q)];
#pragma unroll
        for (int rt = 0; rt < 4; ++rt)
            a[rt] = *(const short8*)&Asb[swz(RA + rt * 16 + r16, kk * 4 + q)];
#pragma unroll
        for (int rt = 0; rt < 4; ++rt)
#pragma unroll
            for (int ct = 0; ct < 4; ++ct)
                acc[rt][ct] = __builtin_amdgcn_mfma_f32_16x16x32_bf16(a[rt], b[ct], acc[rt][ct], 0, 0, 0);
    }
    __syncthreads();  // gemm1 LDS reads done

    // mid = relu(acc + ba) -> Asb (C/D layout -> row-major, swizzled)
    float bav[4];
#pragma unroll
    for (int ct = 0; ct < 4; ++ct) bav[ct] = ba[CB + ct * 16 + r16];
#pragma unroll
    for (int rt = 0; rt < 4; ++rt)
#pragma unroll
        for (int ct = 0; ct < 4; ++ct)
#pragma unroll
            for (int rg = 0; rg < 4; ++rg) {
                float m = fmaxf(acc[rt][ct][rg] + bav[ct], 0.f);
                Asb[swze(RA + rt * 16 + q * 4 + rg, CB + ct * 16 + r16)] = f2bf(m);
            }

    if constexpr (!SECOND) {
        __syncthreads();  // mid fully visible
        const int l16 = t & 15, rr = t >> 4;
        float4 w0 = ((const float4*)w2)[l16 * 2];
        float4 w1 = ((const float4*)w2)[l16 * 2 + 1];
        float b2v = b2[0];
        float s = 0.f, ss = 0.f;
#pragma unroll
        for (int pass = 0; pass < 8; ++pass) {
            int r = pass * 16 + rr;
            int gr = row0 + r;
            short8 v = *(const short8*)&Asb[swz(r, l16)];
            float p = bf2f(v[0]) * w0.x + bf2f(v[1]) * w0.y + bf2f(v[2]) * w0.z +
                      bf2f(v[3]) * w0.w + bf2f(v[4]) * w1.x + bf2f(v[5]) * w1.y +
                      bf2f(v[6]) * w1.z + bf2f(v[7]) * w1.w;
#pragma unroll
            for (int off = 1; off < 16; off <<= 1) p += __shfl_xor(p, off, 16);
            if (l16 == 0 && gr < NN) {
                float h2 = p + b2v;
                z[gr] = h2;
                s += h2;
                ss += h2 * h2;
            }
        }
        s += __shfl_xor(s, 16); s += __shfl_xor(s, 32);
        ss += __shfl_xor(ss, 16); ss += __shfl_xor(ss, 32);
        float* rsm = (float*)Wsb;  // Wsb dead after gemm1
        if ((t & 63) == 0) { rsm[wave * 2] = s; rsm[wave * 2 + 1] = ss; }
        __syncthreads();
        if (t == 0) {
            float S = rsm[0] + rsm[2] + rsm[4] + rsm[6];
            float SS = rsm[1] + rsm[3] + rsm[5] + rsm[7];
            int rp = (blockIdx.x & 7) * 2;
            unsafeAtomicAdd(&s2rep[rp], S);
            unsafeAtomicAdd(&s2rep[rp + 1], SS);
        }
        return;
    } else {
        // write prefetched Wb into Wsb (Wa reads finished at barrier above)
#pragma unroll
        for (int i = 0; i < 8; ++i) {
            int f = i * 256 + t;
            int r = f >> 4, c8 = f & 15;
            *(short8*)&Wsb[swz(r, c8)] = wpre[i];
        }
        __syncthreads();

#pragma unroll
        for (int rt = 0; rt < 4; ++rt)
#pragma unroll
            for (int ct = 0; ct < 4; ++ct) acc[rt][ct] = (f32x4)0.f;

#pragma unroll
        for (int kk = 0; kk < 4; ++kk) {
            short8 b[4], a[4];
#pragma unroll
            for (int ct = 0; ct < 4; ++ct)
                b[ct] = *(const short8*)&Wsb[swz(CB + ct * 16 + r16, kk * 4 + q)];
#pragma unroll
            for (int rt = 0; rt < 4; ++rt)
                a[rt] = *(const short8*)&Asb[swz(RA + rt * 16 + r16, kk * 4 + q)];
#pragma unroll
            for (int rt = 0; rt < 4; ++rt)
#pragma unroll
                for (int ct = 0; ct < 4; ++ct)
                    acc[rt][ct] = __builtin_amdgcn_mfma_f32_16x16x32_bf16(a[rt], b[ct], acc[rt][ct], 0, 0, 0);
        }
        __syncthreads();  // gemm2 LDS reads done

        float bbv[4];
#pragma unroll
        for (int ct = 0; ct < 4; ++ct) bbv[ct] = bb[CB + ct * 16 + r16];
        float s[4] = {0.f, 0.f, 0.f, 0.f}, ss[4] = {0.f, 0.f, 0.f, 0.f};
#pragma unroll
        for (int rt = 0; rt < 4; ++rt)
#pragma unroll
            for (int ct = 0; ct < 4; ++ct)
#pragma unroll
                for (int rg = 0; rg < 4; ++rg) {
                    int lr = RA + rt * 16 + q * 4 + rg;
                    int gr = row0 + lr;
                    float hv = acc[rt][ct][rg] + bbv[ct];
                    if (gr < NN) { s[ct] += hv; ss[ct] += hv * hv; }
                    Asb[swze(lr, CB + ct * 16 + r16)] = f2bf(hv);
                }
#pragma unroll
        for (int ct = 0; ct < 4; ++ct) {
            s[ct] += __shfl_xor(s[ct], 16);
            s[ct] += __shfl_xor(s[ct], 32);
            ss[ct] += __shfl_xor(ss[ct], 16);
            ss[ct] += __shfl_xor(ss[ct], 32);
        }
        float* redF = (float*)Wsb;  // Wsb dead after gemm2
        if (lane < 16) {
#pragma unroll
            for (int ct = 0; ct < 4; ++ct) {
                int col = CB + ct * 16 + r16;
                redF[rh * 256 + col] = s[ct];
                redF[rh * 256 + 128 + col] = ss[ct];
            }
        }
        __syncthreads();
        {
            float v = redF[t] + redF[256 + t];
            unsafeAtomicAdd(&statsRep[(blockIdx.x & 7) * 256 + t], v);
        }
        // coalesced bf16 store of h tile
#pragma unroll
        for (int i = 0; i < 8; ++i) {
            int f = i * 256 + t;
            int r = f >> 4, c8 = f & 15;
            int gr = row0 + r;
            if (gr < NN)
                *(short8*)(hout + (size_t)gr * 128 + c8 * 8) = *(const short8*)&Asb[swz(r, c8)];
        }
    }
}

__device__ __forceinline__ int lbound(const int* __restrict__ b, int val) {
    int lo = 0, hi = NN;
    while (lo < hi) {
        int m = (lo + hi) >> 1;
        if (b[m] < val) lo = m + 1; else hi = m;
    }
    return lo;
}

// fused BN(1) + segment softmax(temp 5): one block per graph (batch sorted)
__global__ void k_softmax(const float* __restrict__ zr, const float* __restrict__ s2rep,
                          const float* __restrict__ g2, const float* __restrict__ be2,
                          const int* __restrict__ batch, float* __restrict__ out) {
    __shared__ float rb[4];
    const int g = blockIdx.x, t = threadIdx.x;
    const int lo = lbound(batch, g), hi = lbound(batch, g + 1);
    float s = 0.f, ssq = 0.f;
#pragma unroll
    for (int i = 0; i < 8; ++i) { s += s2rep[i * 2]; ssq += s2rep[i * 2 + 1]; }
    const float mu = s / (float)NN;
    const float var = ssq / (float)NN - mu * mu;
    const float sc = g2[0] / sqrtf(var + BN_EPS) * 0.2f;
    const float sh = (be2[0] - mu * g2[0] / sqrtf(var + BN_EPS)) * 0.2f;

    float m = -INFINITY;
    for (int i = lo + t; i < hi; i += 256) m = fmaxf(m, fmaf(zr[i], sc, sh));
#pragma unroll
    for (int off = 1; off < 64; off <<= 1) m = fmaxf(m, __shfl_xor(m, off, 64));
    if ((t & 63) == 0) rb[t >> 6] = m;
    __syncthreads();
    float gmax = fmaxf(fmaxf(rb[0], rb[1]), fmaxf(rb[2], rb[3]));
    __syncthreads();

    float sum = 0.f;
    for (int i = lo + t; i < hi; i += 256) {
        float e = expf(fmaf(zr[i], sc, sh) - gmax);
        out[i] = e;
        sum += e;
    }
#pragma unroll
    for (int off = 1; off < 64; off <<= 1) sum += __shfl_xor(sum, off, 64);
    if ((t & 63) == 0) rb[t >> 6] = sum;
    __syncthreads();
    float S = rb[0] + rb[1] + rb[2] + rb[3];
    float inv = 1.0f / (S + 1e-16f);
    for (int i = lo + t; i < hi; i += 256) out[i] *= inv;
}

extern "C" void kernel_launch(void* const* d_in, const int* in_sizes, int n_in,
                              void* d_out, int out_size, void* d_ws, size_t ws_size,
                              hipStream_t stream) {
    const float* x   = (const float*)d_in[0];
    const int* ei    = (const int*)d_in[1];
    const int* batch = (const int*)d_in[2];
    const float *W0a = (const float*)d_in[3],  *b0a = (const float*)d_in[4];
    const float *W0b = (const float*)d_in[5],  *b0b = (const float*)d_in[6];
    const float *g0  = (const float*)d_in[7],  *be0 = (const float*)d_in[8];
    const float *W1a = (const float*)d_in[9],  *b1a = (const float*)d_in[10];
    const float *W1b = (const float*)d_in[11], *b1b = (const float*)d_in[12];
    const float *g1  = (const float*)d_in[13], *be1 = (const float*)d_in[14];
    const float *W2a = (const float*)d_in[15], *b2a = (const float*)d_in[16];
    const float *W2b = (const float*)d_in[17], *b2b = (const float*)d_in[18];
    const float *g2  = (const float*)d_in[19], *be2 = (const float*)d_in[20];
    float* out = (float*)d_out;

    char* wsb = (char*)d_ws;
    short* Abf = (short*)wsb;
    short* Bbf = (short*)(wsb + 25600000);
    float* Zb  = (float*)(wsb + 51200000);
    float* SMf = (float*)(wsb + 51600000);
    float* S0r = SMf;               // 8 x 256
    float* S1r = SMf + 2048;        // 8 x 256
    float* S2r = SMf + 4096;        // 8 x 2
    int* offs  = (int*)(wsb + 51620000);
    int* bsums = (int*)(wsb + 52020004);
    int* csr   = (int*)(wsb + 52020516);
    short* Wt  = (short*)(wsb + 54580544);
    // deg/pos alias Abf during CSR build
    int* deg = (int*)wsb;
    int* pos = (int*)(wsb + 400000);

    const int gE   = (EE + 255) / 256;    // 2500
    const int gG16 = (NN * 16) / 256;     // 6250
    const int gMlp = (NN + 127) / 128;    // 782

    k_setup<<<391, 256, 0, stream>>>(W0a, W0b, W1a, W1b, W2a, Wt, deg, SMf);

    // ---- CSR build (reused all 3 layers) ----
    k_hist<<<gE, 256, 0, stream>>>(ei, deg);
    k_scan1<<<NBLK, 1024, 0, stream>>>(deg, offs, bsums);
    k_scan2<<<1, 128, 0, stream>>>(bsums);
    k_scan3<<<NBLK, 1024, 0, stream>>>(offs, bsums, pos);
    k_fill<<<gE, 256, 0, stream>>>(ei, pos, csr);

    // layer 0
    k_gather0<<<gG16, 256, 0, stream>>>(x, offs, csr, Abf);
    k_mlp<true><<<gMlp, 256, 0, stream>>>(Abf, Wt, b0a, Wt + 16384, b0b, Abf, S0r,
                                          nullptr, nullptr, nullptr, nullptr);
    // layer 1 (BN0+ReLU fused into gather)
    k_gatherb<<<gG16, 256, 0, stream>>>(Abf, offs, csr, S0r, g0, be0, Bbf);
    k_mlp<true><<<gMlp, 256, 0, stream>>>(Bbf, Wt + 2 * 16384, b1a, Wt + 3 * 16384, b1b,
                                          Bbf, S1r, nullptr, nullptr, nullptr, nullptr);
    // layer 2 (BN1+ReLU fused into gather; final linear fused into mlp)
    k_gatherb<<<gG16, 256, 0, stream>>>(Bbf, offs, csr, S1r, g1, be1, Abf);
    k_mlp<false><<<gMlp, 256, 0, stream>>>(Abf, Wt + 4 * 16384, b2a, nullptr, nullptr,
                                           nullptr, nullptr, W2b, b2b, Zb, S2r);

    // fused BN(1) + segment softmax (temperature 5)
    k_softmax<<<GG, 256, 0, stream>>>(Zb, S2r, g2, be2, batch, out);
}